// Round 4
// baseline (240.150 us; speedup 1.0000x reference)
//
#include <hip/hip_runtime.h>
#include <hip/hip_bf16.h>

#define N_NODES 4096
#define C_DIM   512
#define L_DIM   64
#define SPLITS  8
#define KCHUNK  (N_NODES / SPLITS)   // 512

typedef unsigned short u16;
typedef unsigned int   u32;
using bf16x8 = __attribute__((ext_vector_type(8))) __bf16;
using u16x8  = __attribute__((ext_vector_type(8))) unsigned short;
using f32x4  = __attribute__((ext_vector_type(4))) float;

__device__ __forceinline__ float b2f(u16 u) {
    union { unsigned int i; float f; } v; v.i = ((unsigned int)u) << 16; return v.f;
}
__device__ __forceinline__ u16 f2b(float f) {
    __bf16 h = (__bf16)f;                 // RNE
    union { __bf16 h; u16 u; } v; v.h = h; return v.u;
}
__device__ __forceinline__ void gload16(const void* g, void* l) {
    __builtin_amdgcn_global_load_lds((const __attribute__((address_space(1))) void*)g,
                                     (__attribute__((address_space(3))) void*)l,
                                     16, 0, 0);
}
// mode: 0 = bf16 inputs, 1 = f32. adj ~ U[0,1): bf16 u16 <= 0x3F80; f32 low-halves random.
__device__ __forceinline__ int detect_mode_inl(const u16* __restrict__ adj) {
    int m = 0;
#pragma unroll
    for (int i = 0; i < 64; ++i) m |= (adj[i] >= 0x8000) ? 1 : 0;
    return m;
}
__device__ __forceinline__ float ldin(const void* p, int i, int mode) {
    if (mode) return ((const float*)p)[i];
    return b2f(((const u16*)p)[i]);
}

// ---- workspace byte offsets ----
#define OFF_MODE  0
#define OFF_DT    64
#define OFF_BIAS  1024      // 512 f32
#define OFF_BP    4096      // 64 f32
#define OFF_BP1   4608      // 512 f32
#define OFF_WP2   8192      // 512 f32
#define OFF_BP2   10240     // 1 f32
#define OFF_Q     16384
#define OFF_S     32768
#define OFF_DV    49152     // stores 1/d (reciprocal)
#define OFF_WPP   65536     // 16384 u32: packed bf16 k-pairs of Wp
#define OFF_WP1P  131072    // 16384 u32: packed bf16 k-pairs of Wp1
#define OFF_WFT   196608    // 512 KB bf16 Wf^T
#define OFF_TST   9437184   // 4 MB bf16 TsT[c][j] = s[j]*target[j][c]
#define OFF_XB    13631488  // 4 MB bf16 x
#define OFF_ADJB  17825792  // 32 MB bf16 adj (f32 mode); doubles as Pacc (bf16 mode)

// ================= K1: rowsum [0,1024) | x->bf16 [1024,3072) | Wf^T [3072,3328) |
//                      packWp [3328,3392) | packWp1 [3392,3456) | smalls [3456,3463) ====
__global__ __launch_bounds__(256) void k1_prep(const void* __restrict__ adj, const void* __restrict__ x,
        const void* Wp, const void* bp, const void* Wp1, const void* bp1,
        const void* Wp2, const void* bp2, const void* Wf, const void* bfc, const void* dt,
        int* __restrict__ modep,
        float* __restrict__ bp_f, float* __restrict__ bp1_f,
        float* __restrict__ Wp2_f, float* __restrict__ bp2_f,
        float* __restrict__ bias_f, float* __restrict__ dt_f,
        u32* __restrict__ WpP, u32* __restrict__ Wp1P,
        u16* __restrict__ adjb, float* __restrict__ q, u16* __restrict__ xb,
        u16* __restrict__ WfT) {
    __shared__ float tile[32][33];
    int bid = blockIdx.x, tid = threadIdx.x;
    int mode = detect_mode_inl((const u16*)adj);
    if (bid < 1024) {
        // rowsum (+bf16 copy in f32 mode)
        int wave = tid >> 6, lane = tid & 63;
        int row = bid * 4 + wave;
        float acc = 0.f;
        if (mode) {
            const float4* rp = (const float4*)((const float*)adj + (size_t)row * N_NODES);
            ushort4* wp = (ushort4*)(adjb + (size_t)row * N_NODES);
#pragma unroll 8
            for (int it = 0; it < 16; ++it) {
                float4 v = rp[it * 64 + lane];
                acc += (v.x + v.y) + (v.z + v.w);
                ushort4 o; o.x = f2b(v.x); o.y = f2b(v.y); o.z = f2b(v.z); o.w = f2b(v.w);
                wp[it * 64 + lane] = o;
            }
        } else {
            const u16x8* rp = (const u16x8*)((const u16*)adj + (size_t)row * N_NODES);
#pragma unroll
            for (int it = 0; it < 8; ++it) {
                u16x8 v = rp[it * 64 + lane];
#pragma unroll
                for (int e = 0; e < 8; ++e) acc += b2f(v[e]);
            }
        }
#pragma unroll
        for (int off = 32; off > 0; off >>= 1) acc += __shfl_down(acc, off);
        if (lane == 0) q[row] = acc;
    } else if (bid < 3072) {
        if (mode == 0) return;
        int idx = (bid - 1024) * 256 + tid;
        float4 v = ((const float4*)x)[idx];
        ushort4 o; o.x = f2b(v.x); o.y = f2b(v.y); o.z = f2b(v.z); o.w = f2b(v.w);
        ((ushort4*)xb)[idx] = o;
    } else if (bid < 3328) {
        int g = bid - 3072;
        int tx = tid & 31, ty = tid >> 5;
        int x0 = (g & 15) * 32, y0 = (g >> 4) * 32;
        if (mode) {
            const float* src = (const float*)Wf;
#pragma unroll
            for (int r = ty; r < 32; r += 8) tile[r][tx] = src[(size_t)(y0 + r) * C_DIM + x0 + tx];
        } else {
            const u16* src = (const u16*)Wf;
#pragma unroll
            for (int r = ty; r < 32; r += 8) tile[r][tx] = b2f(src[(size_t)(y0 + r) * C_DIM + x0 + tx]);
        }
        __syncthreads();
#pragma unroll
        for (int r = ty; r < 32; r += 8)
            WfT[(size_t)(x0 + r) * C_DIM + y0 + tx] = f2b(tile[tx][r]);
    } else if (bid < 3392) {
        // WpP[k2*64 + j] = pack(Wp[2k2][j], Wp[2k2+1][j])
        int idx = (bid - 3328) * 256 + tid;              // 0..16383
        int k2i = idx >> 6, j = idx & 63;
        float a = ldin(Wp, (2 * k2i) * L_DIM + j, mode);
        float b = ldin(Wp, (2 * k2i + 1) * L_DIM + j, mode);
        WpP[idx] = (u32)f2b(a) | ((u32)f2b(b) << 16);
    } else if (bid < 3456) {
        // Wp1P[jj2*512 + m] = pack(Wp1[2jj2][m], Wp1[2jj2+1][m])
        int idx = (bid - 3392) * 256 + tid;              // 0..16383
        int jj2 = idx >> 9, m = idx & 511;
        float a = ldin(Wp1, (2 * jj2) * C_DIM + m, mode);
        float b = ldin(Wp1, (2 * jj2 + 1) * C_DIM + m, mode);
        Wp1P[idx] = (u32)f2b(a) | ((u32)f2b(b) << 16);
    } else {
        if (bid == 3456 && tid == 0) *modep = mode;
        int idx = (bid - 3456) * 256 + tid;
        if (idx < 64)           bp_f[idx]          = ldin(bp,  idx, mode);
        else if (idx < 576)     bp1_f[idx - 64]    = ldin(bp1, idx - 64, mode);
        else if (idx < 1088)    Wp2_f[idx - 576]   = ldin(Wp2, idx - 576, mode);
        else if (idx == 1088)   bp2_f[0]           = ldin(bp2, 0, mode);
        else if (idx < 1601)    bias_f[idx - 1089] = ldin(bfc, idx - 1089, mode);
        else if (idx == 1601)   dt_f[0]            = ldin(dt, 0, mode);
    }
}

// ================= K1p: pi-MLP (512 blocks x 8 rows), packed bf16 weights; writes s = pi/q ====
__global__ __launch_bounds__(256) void k1p_pi(const void* __restrict__ xraw,
        const int* __restrict__ modep, const u16* __restrict__ xb,
        const u32* __restrict__ WpP, const u32* __restrict__ Wp1P,
        const float* __restrict__ bp_f,  const float* __restrict__ bp1_f,
        const float* __restrict__ Wp2_f, const float* __restrict__ bp2_f,
        const float* __restrict__ q, float* __restrict__ s) {
    __shared__ __align__(16) char smem[26880];
    int bid = blockIdx.x, tid = threadIdx.x;
    int mode = *modep;
    float (*sx)[C_DIM]      = (float(*)[C_DIM])smem;                 // 16 KB
    float (*red)[8][L_DIM]  = (float(*)[8][L_DIM])(smem + 16384);    // 8 KB
    float (*sz)[L_DIM]      = (float(*)[L_DIM])(smem + 24576);       // 2 KB
    float (*rw)[8]          = (float(*)[8])(smem + 26624);           // 128 B
    int i0 = bid * 8;
    const u16* xsrc = mode ? xb : (const u16*)xraw;
    const u16x8* xp = (const u16x8*)(xsrc + (size_t)i0 * C_DIM);
#pragma unroll
    for (int r = 0; r < 2; ++r) {
        u16x8 v = xp[tid + 256 * r];
        float* dstf = &sx[0][0] + (size_t)(tid + 256 * r) * 8;
#pragma unroll
        for (int e = 0; e < 8; ++e) dstf[e] = b2f(v[e]);
    }
    __syncthreads();
    // z-phase: thread (part = tid>>6, j = tid&63) covers k in [part*128, +128)
    int j = tid & 63, part = tid >> 6;
    float za[8];
#pragma unroll
    for (int n = 0; n < 8; ++n) za[n] = 0.f;
    const u32* wp = WpP + part * 4096 + j;
#pragma unroll 8
    for (int kk = 0; kk < 64; ++kk) {
        u32 w = wp[kk * 64];
        float wa = b2f((u16)(w & 0xFFFF)), wb = b2f((u16)(w >> 16));
        int k = part * 128 + kk * 2;
#pragma unroll
        for (int n = 0; n < 8; ++n) za[n] += sx[n][k] * wa + sx[n][k + 1] * wb;
    }
#pragma unroll
    for (int n = 0; n < 8; ++n) red[part][n][j] = za[n];
    __syncthreads();
#pragma unroll
    for (int r = 0; r < 2; ++r) {
        int idx = tid + r * 256; int n = idx >> 6, jj = idx & 63;
        sz[n][jj] = red[0][n][jj] + red[1][n][jj] + red[2][n][jj] + red[3][n][jj] + bp_f[jj];
    }
    __syncthreads();
    // h-phase: thread owns m0 = tid, m1 = tid+256
    int m0 = tid, m1 = tid + 256;
    float h0[8], h1[8];
    float b0 = bp1_f[m0], b1 = bp1_f[m1];
#pragma unroll
    for (int n = 0; n < 8; ++n) { h0[n] = b0; h1[n] = b1; }
    const u32* w1p = Wp1P + m0;
#pragma unroll 4
    for (int jj2 = 0; jj2 < 32; ++jj2) {
        u32 w0 = w1p[jj2 * 512], w1 = w1p[jj2 * 512 + 256];
        float w0a = b2f((u16)(w0 & 0xFFFF)), w0b = b2f((u16)(w0 >> 16));
        float w1a = b2f((u16)(w1 & 0xFFFF)), w1b = b2f((u16)(w1 >> 16));
#pragma unroll
        for (int n = 0; n < 8; ++n) {
            float za_ = sz[n][2 * jj2], zb_ = sz[n][2 * jj2 + 1];
            h0[n] += za_ * w0a + zb_ * w0b;
            h1[n] += za_ * w1a + zb_ * w1b;
        }
    }
    float w2a = Wp2_f[m0], w2b = Wp2_f[m1];
    float p[8];
#pragma unroll
    for (int n = 0; n < 8; ++n)
        p[n] = fmaxf(h0[n], 0.f) * w2a + fmaxf(h1[n], 0.f) * w2b;
#pragma unroll
    for (int off = 32; off > 0; off >>= 1)
#pragma unroll
        for (int n = 0; n < 8; ++n) p[n] += __shfl_down(p[n], off);
    int lane = tid & 63, wave = tid >> 6;
    if (lane == 0) {
#pragma unroll
        for (int n = 0; n < 8; ++n) rw[wave][n] = p[n];
    }
    __syncthreads();
    if (tid < 8) {
        float tot = rw[0][tid] + rw[1][tid] + rw[2][tid] + rw[3][tid] + bp2_f[0];
        float pi = 1.f / (1.f + expf(-tot));
        s[i0 + tid] = pi / q[i0 + tid];
    }
}

// ================= K2: dvec [0,1024) | gemm1 BK=64 swizzled + fused s-scale/transpose [1024,1536) ====
__global__ __launch_bounds__(256) void k2_mid(const void* __restrict__ adjraw, const void* __restrict__ xraw,
        const int* __restrict__ modep,
        const float* __restrict__ s, const float* __restrict__ bias_f, const float* __restrict__ dt_f,
        const u16* __restrict__ adjb, const u16* __restrict__ xb, const u16* __restrict__ WfT,
        float* __restrict__ dv, u16* __restrict__ TsT,
        void* __restrict__ out, float* __restrict__ Pacc) {
    __shared__ __align__(16) char smem[16640];
    int bid = blockIdx.x, tid = threadIdx.x;
    int mode = *modep;
    if (bid < 1024) {
        // dvec: dv = 1 / (adj @ s + 1e-5)  (store reciprocal)
        float* s_lds = (float*)smem;                     // 16 KB
#pragma unroll
        for (int r = 0; r < 4; ++r) ((float4*)s_lds)[tid + 256 * r] = ((const float4*)s)[tid + 256 * r];
        __syncthreads();
        const u16* A = mode ? adjb : (const u16*)adjraw;
        int wave = tid >> 6, lane = tid & 63;
        int row = bid * 4 + wave;
        const u16x8* rp = (const u16x8*)(A + (size_t)row * N_NODES);
        float acc = 0.f;
#pragma unroll
        for (int it = 0; it < 8; ++it) {
            int chunk = it * 64 + lane;
            u16x8 v = rp[chunk];
            const float4* sp = (const float4*)(s_lds + chunk * 8);
            float4 s0 = sp[0], s1 = sp[1];
            acc += b2f(v[0]) * s0.x + b2f(v[1]) * s0.y + b2f(v[2]) * s0.z + b2f(v[3]) * s0.w;
            acc += b2f(v[4]) * s1.x + b2f(v[5]) * s1.y + b2f(v[6]) * s1.z + b2f(v[7]) * s1.w;
        }
#pragma unroll
        for (int off = 32; off > 0; off >>= 1) acc += __shfl_down(acc, off);
        if (lane == 0) dv[row] = 1.f / (acc + 1e-5f);
    } else {
        // gemm1: 64x64 tile, K=512, BK=64, single-buffer, slot-XOR swizzled LDS (conflict-free).
        // t = relu(acc+bias); out = (1-dt)*t; TsT[col][row] = bf16(t*s[row])
        u16* lA = (u16*)smem;                    // 8 KB: 64 rows x 64 elem
        u16* lB = (u16*)(smem + 8192);           // 8 KB
        u16* lT = (u16*)smem;                    // 8 KB, aliases lA after main loop
        float* s_row = (float*)(smem + 16384);   // 256 B
        int g = bid - 1024;
        int lane = tid & 63, wave = tid >> 6;
        int bm = (g & 63) * 64, bn = (g >> 6) * 64;
        if (tid < 64) s_row[tid] = s[bm + tid];
        const u16* Axb = mode ? xb : (const u16*)xraw;
        float* tgt = mode ? (float*)out : Pacc;
        int quad = lane >> 4, l15 = lane & 15;
        int wm = wave * 16;
        int trow = tid >> 3;                       // 0..31
        int xslot = (tid & 7) ^ (trow & 7);        // inverse-swizzled global slot
        const u16* Ap0 = Axb + (size_t)(bm + trow) * C_DIM + xslot * 8;
        const u16* Ap1 = Axb + (size_t)(bm + 32 + trow) * C_DIM + xslot * 8;
        const u16* Bp0 = WfT + (size_t)(bn + trow) * C_DIM + xslot * 8;
        const u16* Bp1 = WfT + (size_t)(bn + 32 + trow) * C_DIM + xslot * 8;
        f32x4 acc[4];
#pragma unroll
        for (int nt = 0; nt < 4; ++nt) acc[nt] = (f32x4){0.f, 0.f, 0.f, 0.f};
        for (int k0 = 0; k0 < C_DIM; k0 += 64) {
            gload16(Ap0 + k0, lA + tid * 8);
            gload16(Ap1 + k0, lA + 2048 + tid * 8);
            gload16(Bp0 + k0, lB + tid * 8);
            gload16(Bp1 + k0, lB + 2048 + tid * 8);
            asm volatile("s_waitcnt vmcnt(0)\n\ts_barrier" ::: "memory");
            __builtin_amdgcn_sched_barrier(0);
#pragma unroll
            for (int kk = 0; kk < 2; ++kk) {
                int xr = (((kk << 2) | quad) ^ (l15 & 7)) * 8;
                bf16x8 af = *(const bf16x8*)&lA[(wm + l15) * 64 + xr];
                bf16x8 bfv[4];
#pragma unroll
                for (int nt = 0; nt < 4; ++nt)
                    bfv[nt] = *(const bf16x8*)&lB[(nt * 16 + l15) * 64 + xr];
#pragma unroll
                for (int nt = 0; nt < 4; ++nt)
                    acc[nt] = __builtin_amdgcn_mfma_f32_16x16x32_bf16(af, bfv[nt], acc[nt], 0, 0, 0);
            }
            asm volatile("s_waitcnt lgkmcnt(0)\n\ts_barrier" ::: "memory");
        }
        float c0 = 1.f - dt_f[0];
#pragma unroll
        for (int nt = 0; nt < 4; ++nt) {
            int col_l = nt * 16 + l15;
            float bv = bias_f[bn + col_l];
#pragma unroll
            for (int r = 0; r < 4; ++r) {
                int row_l = wm + quad * 4 + r;
                float t = fmaxf(acc[nt][r] + bv, 0.f);
                tgt[(size_t)(bm + row_l) * C_DIM + bn + col_l] = c0 * t;
                lT[col_l * 64 + row_l] = f2b(t * s_row[row_l]);
            }
        }
        __syncthreads();
        // coalesced transposed store: thread -> (col_l = tid>>2, 16-row segment = tid&3)
        int col_l = tid >> 2, seg = tid & 3;
        uint4 w0 = *(const uint4*)&lT[col_l * 64 + seg * 16];
        uint4 w1 = *(const uint4*)&lT[col_l * 64 + seg * 16 + 8];
        u16* dst = TsT + (size_t)(bn + col_l) * N_NODES + bm + seg * 16;
        *(uint4*)dst = w0;
        *(uint4*)(dst + 8) = w1;
    }
}

// ================= K3: gemm2 split-K=8, 128x128 tile, BK=64, single 32KB LDS buffer,
// slot-XOR swizzle (conflict-free ds_read_b128), XCD-aware block remap for L2 locality.
__global__ __launch_bounds__(256) void k3_gemm2(const void* __restrict__ adjraw,
        const int* __restrict__ modep,
        const u16* __restrict__ adjb, const u16* __restrict__ TsT,
        const float* __restrict__ dv, const float* __restrict__ dt_f,
        void* __restrict__ out, float* __restrict__ Pacc) {
    __shared__ __align__(16) u16 lA[8192];   // 16 KB: 128 rows x 64 elem, slot-XOR layout
    __shared__ __align__(16) u16 lB[8192];   // 16 KB
    int mode = *modep;
    const u16* A = mode ? adjb : (const u16*)adjraw;
    float* tgt = mode ? (float*)out : Pacc;
    int tid = threadIdx.x;
    int lane = tid & 63, wave = tid >> 6;
    // XCD-aware remap: 1024 blocks, 8 XCDs -> XCD k owns nid [k*128,(k+1)*128):
    // nid: z = nid&7, bn = (nid>>3)&3, bm = nid>>5  => per XCD: 4 bm-strips x all bn x all z
    int id = blockIdx.x;
    int nid = (id & 7) * 128 + (id >> 3);
    int kbase = (nid & 7) * KCHUNK;
    int bn = ((nid >> 3) & 3) * 128;
    int bm = (nid >> 5) * 128;
    int wm = (wave & 1) * 64, wn = (wave >> 1) * 64;
    int quad = lane >> 4, l15 = lane & 15;
    int trow = tid >> 3;                       // 0..31
    int xslot = (tid & 7) ^ (trow & 7);        // inverse-swizzled global slot

    const u16* Ap[4]; const u16* Bp[4];
#pragma unroll
    for (int i = 0; i < 4; ++i) {
        Ap[i] = A   + (size_t)(bm + i * 32 + trow) * N_NODES + kbase + xslot * 8;
        Bp[i] = TsT + (size_t)(bn + i * 32 + trow) * N_NODES + kbase + xslot * 8;
    }

    f32x4 acc[4][4];
#pragma unroll
    for (int a = 0; a < 4; ++a)
#pragma unroll
        for (int b = 0; b < 4; ++b) acc[a][b] = (f32x4){0.f, 0.f, 0.f, 0.f};

    for (int k0 = 0; k0 < KCHUNK; k0 += 64) {
#pragma unroll
        for (int i = 0; i < 4; ++i) gload16(Ap[i] + k0, lA + i * 2048 + tid * 8);
#pragma unroll
        for (int i = 0; i < 4; ++i) gload16(Bp[i] + k0, lB + i * 2048 + tid * 8);
        asm volatile("s_waitcnt vmcnt(0)\n\ts_barrier" ::: "memory");
        __builtin_amdgcn_sched_barrier(0);
#pragma unroll
        for (int kk = 0; kk < 2; ++kk) {
            int xr = (((kk << 2) | quad) ^ (l15 & 7)) * 8;
            bf16x8 af[4], bfv[4];
#pragma unroll
            for (int mt = 0; mt < 4; ++mt) af[mt] = *(const bf16x8*)&lA[(wm + mt * 16 + l15) * 64 + xr];
#pragma unroll
            for (int nt = 0; nt < 4; ++nt) bfv[nt] = *(const bf16x8*)&lB[(wn + nt * 16 + l15) * 64 + xr];
#pragma unroll
            for (int mt = 0; mt < 4; ++mt)
#pragma unroll
                for (int nt = 0; nt < 4; ++nt)
                    acc[mt][nt] = __builtin_amdgcn_mfma_f32_16x16x32_bf16(af[mt], bfv[nt], acc[mt][nt], 0, 0, 0);
        }
        asm volatile("s_waitcnt lgkmcnt(0)\n\ts_barrier" ::: "memory");
    }

    float c1 = dt_f[0] * 4.f;  // dt / EPS
#pragma unroll
    for (int mt = 0; mt < 4; ++mt) {
        float inv[4];
#pragma unroll
        for (int r = 0; r < 4; ++r) inv[r] = c1 * dv[bm + wm + mt * 16 + quad * 4 + r];
#pragma unroll
        for (int nt = 0; nt < 4; ++nt) {
            int col = bn + wn + nt * 16 + l15;
#pragma unroll
            for (int r = 0; r < 4; ++r) {
                int row = bm + wm + mt * 16 + quad * 4 + r;
                atomicAdd(&tgt[(size_t)row * C_DIM + col], acc[mt][nt][r] * inv[r]);
            }
        }
    }
}

// ================= K5: bf16 finalize (early-exit in f32 mode) =================
__global__ __launch_bounds__(256) void k5_fin(const int* __restrict__ modep,
                                              const float* __restrict__ Pacc,
                                              u16* __restrict__ out) {
    if (*modep) return;
    int idx = blockIdx.x * 256 + threadIdx.x;
    float4 v = ((const float4*)Pacc)[idx];
    ushort4 o; o.x = f2b(v.x); o.y = f2b(v.y); o.z = f2b(v.z); o.w = f2b(v.w);
    ((ushort4*)out)[idx] = o;
}

extern "C" void kernel_launch(void* const* d_in, const int* in_sizes, int n_in,
                              void* d_out, int out_size, void* d_ws, size_t ws_size,
                              hipStream_t stream) {
    const void* x   = d_in[0];
    const void* adj = d_in[1];
    const void* Wp  = d_in[2];
    const void* bp  = d_in[3];
    const void* Wp1 = d_in[4];
    const void* bp1 = d_in[5];
    const void* Wp2 = d_in[6];
    const void* bp2 = d_in[7];
    const void* Wf  = d_in[8];
    const void* bfc = d_in[9];
    const void* dtp = d_in[10];

    char* ws = (char*)d_ws;
    int*   modep  = (int*)(ws + OFF_MODE);
    float* dt_f   = (float*)(ws + OFF_DT);
    float* bias_f = (float*)(ws + OFF_BIAS);
    float* bp_f   = (float*)(ws + OFF_BP);
    float* bp1_f  = (float*)(ws + OFF_BP1);
    float* Wp2_f  = (float*)(ws + OFF_WP2);
    float* bp2_f  = (float*)(ws + OFF_BP2);
    float* q      = (float*)(ws + OFF_Q);
    float* s      = (float*)(ws + OFF_S);
    float* dv     = (float*)(ws + OFF_DV);
    u32*   WpP    = (u32*)(ws + OFF_WPP);
    u32*   Wp1P   = (u32*)(ws + OFF_WP1P);
    u16*   WfT    = (u16*)(ws + OFF_WFT);
    u16*   TsT    = (u16*)(ws + OFF_TST);
    u16*   xb     = (u16*)(ws + OFF_XB);
    u16*   adjb   = (u16*)(ws + OFF_ADJB);
    float* Pacc   = (float*)(ws + OFF_ADJB);   // bf16 mode only: adjb unused there

    k1_prep<<<3463, 256, 0, stream>>>(adj, x, Wp, bp, Wp1, bp1, Wp2, bp2, Wf, bfc, dtp,
                                      modep, bp_f, bp1_f, Wp2_f, bp2_f, bias_f, dt_f,
                                      WpP, Wp1P, adjb, q, xb, WfT);
    k1p_pi<<<512, 256, 0, stream>>>(x, modep, xb, WpP, Wp1P, bp_f, bp1_f, Wp2_f, bp2_f, q, s);
    k2_mid<<<1536, 256, 0, stream>>>(adj, x, modep, s, bias_f, dt_f, adjb, xb, WfT,
                                     dv, TsT, d_out, Pacc);
    k3_gemm2<<<1024, 256, 0, stream>>>(adj, modep, adjb, TsT, dv, dt_f, d_out, Pacc);
    k5_fin<<<2048, 256, 0, stream>>>(modep, Pacc, (u16*)d_out);
}

// Round 5
// 234.515 us; speedup vs baseline: 1.0240x; 1.0240x over previous
//
#include <hip/hip_runtime.h>
#include <hip/hip_bf16.h>

#define N_NODES 4096
#define C_DIM   512
#define L_DIM   64
#define SPLITS  4
#define KCHUNK  (N_NODES / SPLITS)   // 1024

typedef unsigned short u16;
typedef unsigned int   u32;
using bf16x8 = __attribute__((ext_vector_type(8))) __bf16;
using u16x8  = __attribute__((ext_vector_type(8))) unsigned short;
using f32x4  = __attribute__((ext_vector_type(4))) float;

__device__ __forceinline__ float b2f(u16 u) {
    union { unsigned int i; float f; } v; v.i = ((unsigned int)u) << 16; return v.f;
}
__device__ __forceinline__ u16 f2b(float f) {
    __bf16 h = (__bf16)f;                 // RNE
    union { __bf16 h; u16 u; } v; v.h = h; return v.u;
}
__device__ __forceinline__ void gload16(const void* g, void* l) {
    __builtin_amdgcn_global_load_lds((const __attribute__((address_space(1))) void*)g,
                                     (__attribute__((address_space(3))) void*)l,
                                     16, 0, 0);
}
// mode: 0 = bf16 inputs, 1 = f32. adj ~ U[0,1): bf16 u16 <= 0x3F80; f32 low-halves random.
__device__ __forceinline__ int detect_mode_inl(const u16* __restrict__ adj) {
    int m = 0;
#pragma unroll
    for (int i = 0; i < 64; ++i) m |= (adj[i] >= 0x8000) ? 1 : 0;
    return m;
}
__device__ __forceinline__ float ldin(const void* p, int i, int mode) {
    if (mode) return ((const float*)p)[i];
    return b2f(((const u16*)p)[i]);
}

// ---- workspace byte offsets ----
#define OFF_MODE  0
#define OFF_DT    64
#define OFF_BIAS  1024      // 512 f32
#define OFF_BP    4096      // 64 f32
#define OFF_BP1   4608      // 512 f32
#define OFF_WP2   8192      // 512 f32
#define OFF_BP2   10240     // 1 f32
#define OFF_Q     16384
#define OFF_S     32768
#define OFF_DV    49152     // 4096 f32: RAW d partial sums (zero-filled by k1)
#define OFF_WPP   65536     // 16384 u32: packed bf16 k-pairs of Wp
#define OFF_WP1P  131072    // 16384 u32: packed bf16 k-pairs of Wp1
#define OFF_WFT   196608    // 512 KB bf16 Wf^T -> ends 720896
#define OFF_PACC  720896    // 8 MB f32: raw P accumulator (zero-filled by k1) -> ends 9109504
#define OFF_TST   9437184   // 4 MB bf16 TsT[c][j] = s[j]*target[j][c]
#define OFF_XB    13631488  // 4 MB bf16 x
#define OFF_ADJB  17825792  // 32 MB bf16 adj (f32 mode); first 8MB doubles as f32 base (bf16 mode)

// ================= K1: rowsum [0,1024) | x->bf16 [1024,3072) | Wf^T [3072,3328) |
//   packWp [3328,3392) | packWp1 [3392,3456) | smalls [3456,3463) |
//   Pacc zero [3463,5511) | dvraw zero [5511,5527) ====
__global__ __launch_bounds__(256) void k1_prep(const void* __restrict__ adj, const void* __restrict__ x,
        const void* Wp, const void* bp, const void* Wp1, const void* bp1,
        const void* Wp2, const void* bp2, const void* Wf, const void* bfc, const void* dt,
        int* __restrict__ modep,
        float* __restrict__ bp_f, float* __restrict__ bp1_f,
        float* __restrict__ Wp2_f, float* __restrict__ bp2_f,
        float* __restrict__ bias_f, float* __restrict__ dt_f,
        u32* __restrict__ WpP, u32* __restrict__ Wp1P,
        u16* __restrict__ adjb, float* __restrict__ q, u16* __restrict__ xb,
        u16* __restrict__ WfT, float* __restrict__ Pacc2, float* __restrict__ dvraw) {
    __shared__ float tile[32][33];
    int bid = blockIdx.x, tid = threadIdx.x;
    int mode = detect_mode_inl((const u16*)adj);
    if (bid < 1024) {
        // rowsum (+bf16 copy in f32 mode)
        int wave = tid >> 6, lane = tid & 63;
        int row = bid * 4 + wave;
        float acc = 0.f;
        if (mode) {
            const float4* rp = (const float4*)((const float*)adj + (size_t)row * N_NODES);
            ushort4* wp = (ushort4*)(adjb + (size_t)row * N_NODES);
#pragma unroll 8
            for (int it = 0; it < 16; ++it) {
                float4 v = rp[it * 64 + lane];
                acc += (v.x + v.y) + (v.z + v.w);
                ushort4 o; o.x = f2b(v.x); o.y = f2b(v.y); o.z = f2b(v.z); o.w = f2b(v.w);
                wp[it * 64 + lane] = o;
            }
        } else {
            const u16x8* rp = (const u16x8*)((const u16*)adj + (size_t)row * N_NODES);
#pragma unroll
            for (int it = 0; it < 8; ++it) {
                u16x8 v = rp[it * 64 + lane];
#pragma unroll
                for (int e = 0; e < 8; ++e) acc += b2f(v[e]);
            }
        }
#pragma unroll
        for (int off = 32; off > 0; off >>= 1) acc += __shfl_down(acc, off);
        if (lane == 0) q[row] = acc;
    } else if (bid < 3072) {
        if (mode == 0) return;
        int idx = (bid - 1024) * 256 + tid;
        float4 v = ((const float4*)x)[idx];
        ushort4 o; o.x = f2b(v.x); o.y = f2b(v.y); o.z = f2b(v.z); o.w = f2b(v.w);
        ((ushort4*)xb)[idx] = o;
    } else if (bid < 3328) {
        int g = bid - 3072;
        int tx = tid & 31, ty = tid >> 5;
        int x0 = (g & 15) * 32, y0 = (g >> 4) * 32;
        if (mode) {
            const float* src = (const float*)Wf;
#pragma unroll
            for (int r = ty; r < 32; r += 8) tile[r][tx] = src[(size_t)(y0 + r) * C_DIM + x0 + tx];
        } else {
            const u16* src = (const u16*)Wf;
#pragma unroll
            for (int r = ty; r < 32; r += 8) tile[r][tx] = b2f(src[(size_t)(y0 + r) * C_DIM + x0 + tx]);
        }
        __syncthreads();
#pragma unroll
        for (int r = ty; r < 32; r += 8)
            WfT[(size_t)(x0 + r) * C_DIM + y0 + tx] = f2b(tile[tx][r]);
    } else if (bid < 3392) {
        // WpP[k2*64 + j] = pack(Wp[2k2][j], Wp[2k2+1][j])
        int idx = (bid - 3328) * 256 + tid;              // 0..16383
        int k2i = idx >> 6, j = idx & 63;
        float a = ldin(Wp, (2 * k2i) * L_DIM + j, mode);
        float b = ldin(Wp, (2 * k2i + 1) * L_DIM + j, mode);
        WpP[idx] = (u32)f2b(a) | ((u32)f2b(b) << 16);
    } else if (bid < 3456) {
        // Wp1P[jj2*512 + m] = pack(Wp1[2jj2][m], Wp1[2jj2+1][m])
        int idx = (bid - 3392) * 256 + tid;              // 0..16383
        int jj2 = idx >> 9, m = idx & 511;
        float a = ldin(Wp1, (2 * jj2) * C_DIM + m, mode);
        float b = ldin(Wp1, (2 * jj2 + 1) * C_DIM + m, mode);
        Wp1P[idx] = (u32)f2b(a) | ((u32)f2b(b) << 16);
    } else if (bid < 3463) {
        if (bid == 3456 && tid == 0) *modep = mode;
        int idx = (bid - 3456) * 256 + tid;
        if (idx < 64)           bp_f[idx]          = ldin(bp,  idx, mode);
        else if (idx < 576)     bp1_f[idx - 64]    = ldin(bp1, idx - 64, mode);
        else if (idx < 1088)    Wp2_f[idx - 576]   = ldin(Wp2, idx - 576, mode);
        else if (idx == 1088)   bp2_f[0]           = ldin(bp2, 0, mode);
        else if (idx < 1601)    bias_f[idx - 1089] = ldin(bfc, idx - 1089, mode);
        else if (idx == 1601)   dt_f[0]            = ldin(dt, 0, mode);
    } else if (bid < 5511) {
        int idx = (bid - 3463) * 256 + tid;              // 0..524287 (f32x4) = 8 MB
        ((float4*)Pacc2)[idx] = make_float4(0.f, 0.f, 0.f, 0.f);
    } else {
        int idx = (bid - 5511) * 256 + tid;              // 0..4095
        dvraw[idx] = 0.f;
    }
}

// ================= K1p: pi-MLP (512 blocks x 8 rows), packed bf16 weights; writes s = pi/q ====
__global__ __launch_bounds__(256) void k1p_pi(const void* __restrict__ xraw,
        const int* __restrict__ modep, const u16* __restrict__ xb,
        const u32* __restrict__ WpP, const u32* __restrict__ Wp1P,
        const float* __restrict__ bp_f,  const float* __restrict__ bp1_f,
        const float* __restrict__ Wp2_f, const float* __restrict__ bp2_f,
        const float* __restrict__ q, float* __restrict__ s) {
    __shared__ __align__(16) char smem[26880];
    int bid = blockIdx.x, tid = threadIdx.x;
    int mode = *modep;
    float (*sx)[C_DIM]      = (float(*)[C_DIM])smem;                 // 16 KB
    float (*red)[8][L_DIM]  = (float(*)[8][L_DIM])(smem + 16384);    // 8 KB
    float (*sz)[L_DIM]      = (float(*)[L_DIM])(smem + 24576);       // 2 KB
    float (*rw)[8]          = (float(*)[8])(smem + 26624);           // 128 B
    int i0 = bid * 8;
    const u16* xsrc = mode ? xb : (const u16*)xraw;
    const u16x8* xp = (const u16x8*)(xsrc + (size_t)i0 * C_DIM);
#pragma unroll
    for (int r = 0; r < 2; ++r) {
        u16x8 v = xp[tid + 256 * r];
        float* dstf = &sx[0][0] + (size_t)(tid + 256 * r) * 8;
#pragma unroll
        for (int e = 0; e < 8; ++e) dstf[e] = b2f(v[e]);
    }
    __syncthreads();
    // z-phase: thread (part = tid>>6, j = tid&63) covers k in [part*128, +128)
    int j = tid & 63, part = tid >> 6;
    float za[8];
#pragma unroll
    for (int n = 0; n < 8; ++n) za[n] = 0.f;
    const u32* wp = WpP + part * 4096 + j;
#pragma unroll 8
    for (int kk = 0; kk < 64; ++kk) {
        u32 w = wp[kk * 64];
        float wa = b2f((u16)(w & 0xFFFF)), wb = b2f((u16)(w >> 16));
        int k = part * 128 + kk * 2;
#pragma unroll
        for (int n = 0; n < 8; ++n) za[n] += sx[n][k] * wa + sx[n][k + 1] * wb;
    }
#pragma unroll
    for (int n = 0; n < 8; ++n) red[part][n][j] = za[n];
    __syncthreads();
#pragma unroll
    for (int r = 0; r < 2; ++r) {
        int idx = tid + r * 256; int n = idx >> 6, jj = idx & 63;
        sz[n][jj] = red[0][n][jj] + red[1][n][jj] + red[2][n][jj] + red[3][n][jj] + bp_f[jj];
    }
    __syncthreads();
    // h-phase: thread owns m0 = tid, m1 = tid+256
    int m0 = tid, m1 = tid + 256;
    float h0[8], h1[8];
    float b0 = bp1_f[m0], b1 = bp1_f[m1];
#pragma unroll
    for (int n = 0; n < 8; ++n) { h0[n] = b0; h1[n] = b1; }
    const u32* w1p = Wp1P + m0;
#pragma unroll 4
    for (int jj2 = 0; jj2 < 32; ++jj2) {
        u32 w0 = w1p[jj2 * 512], w1 = w1p[jj2 * 512 + 256];
        float w0a = b2f((u16)(w0 & 0xFFFF)), w0b = b2f((u16)(w0 >> 16));
        float w1a = b2f((u16)(w1 & 0xFFFF)), w1b = b2f((u16)(w1 >> 16));
#pragma unroll
        for (int n = 0; n < 8; ++n) {
            float za_ = sz[n][2 * jj2], zb_ = sz[n][2 * jj2 + 1];
            h0[n] += za_ * w0a + zb_ * w0b;
            h1[n] += za_ * w1a + zb_ * w1b;
        }
    }
    float w2a = Wp2_f[m0], w2b = Wp2_f[m1];
    float p[8];
#pragma unroll
    for (int n = 0; n < 8; ++n)
        p[n] = fmaxf(h0[n], 0.f) * w2a + fmaxf(h1[n], 0.f) * w2b;
#pragma unroll
    for (int off = 32; off > 0; off >>= 1)
#pragma unroll
        for (int n = 0; n < 8; ++n) p[n] += __shfl_down(p[n], off);
    int lane = tid & 63, wave = tid >> 6;
    if (lane == 0) {
#pragma unroll
        for (int n = 0; n < 8; ++n) rw[wave][n] = p[n];
    }
    __syncthreads();
    if (tid < 8) {
        float tot = rw[0][tid] + rw[1][tid] + rw[2][tid] + rw[3][tid] + bp2_f[0];
        float pi = 1.f / (1.f + expf(-tot));
        s[i0 + tid] = pi / q[i0 + tid];
    }
}

// ================= K2: gemm1 BK=64 swizzled + fused s-scale/transpose (512 blocks) ====
// base = (1-dt)*t -> out (f32 mode) / Pacc_base (bf16 mode); TsT[col][row] = bf16(t*s[row])
__global__ __launch_bounds__(256) void k2_gemm1(const void* __restrict__ xraw,
        const int* __restrict__ modep,
        const float* __restrict__ s, const float* __restrict__ bias_f, const float* __restrict__ dt_f,
        const u16* __restrict__ xb, const u16* __restrict__ WfT,
        u16* __restrict__ TsT, void* __restrict__ out, float* __restrict__ Pacc_base) {
    __shared__ __align__(16) char smem[16640];
    int bid = blockIdx.x, tid = threadIdx.x;
    int mode = *modep;
    u16* lA = (u16*)smem;                    // 8 KB: 64 rows x 64 elem
    u16* lB = (u16*)(smem + 8192);           // 8 KB
    u16* lT = (u16*)smem;                    // 8 KB, aliases lA after main loop
    float* s_row = (float*)(smem + 16384);   // 256 B
    int lane = tid & 63, wave = tid >> 6;
    int bm = (bid & 63) * 64, bn = (bid >> 6) * 64;
    if (tid < 64) s_row[tid] = s[bm + tid];
    const u16* Axb = mode ? xb : (const u16*)xraw;
    float* basep = mode ? (float*)out : Pacc_base;
    int quad = lane >> 4, l15 = lane & 15;
    int wm = wave * 16;
    int trow = tid >> 3;                       // 0..31
    int xslot = (tid & 7) ^ (trow & 7);        // inverse-swizzled global slot
    const u16* Ap0 = Axb + (size_t)(bm + trow) * C_DIM + xslot * 8;
    const u16* Ap1 = Axb + (size_t)(bm + 32 + trow) * C_DIM + xslot * 8;
    const u16* Bp0 = WfT + (size_t)(bn + trow) * C_DIM + xslot * 8;
    const u16* Bp1 = WfT + (size_t)(bn + 32 + trow) * C_DIM + xslot * 8;
    f32x4 acc[4];
#pragma unroll
    for (int nt = 0; nt < 4; ++nt) acc[nt] = (f32x4){0.f, 0.f, 0.f, 0.f};
    for (int k0 = 0; k0 < C_DIM; k0 += 64) {
        gload16(Ap0 + k0, lA + tid * 8);
        gload16(Ap1 + k0, lA + 2048 + tid * 8);
        gload16(Bp0 + k0, lB + tid * 8);
        gload16(Bp1 + k0, lB + 2048 + tid * 8);
        asm volatile("s_waitcnt vmcnt(0)\n\ts_barrier" ::: "memory");
        __builtin_amdgcn_sched_barrier(0);
#pragma unroll
        for (int kk = 0; kk < 2; ++kk) {
            int xr = (((kk << 2) | quad) ^ (l15 & 7)) * 8;
            bf16x8 af = *(const bf16x8*)&lA[(wm + l15) * 64 + xr];
            bf16x8 bfv[4];
#pragma unroll
            for (int nt = 0; nt < 4; ++nt)
                bfv[nt] = *(const bf16x8*)&lB[(nt * 16 + l15) * 64 + xr];
#pragma unroll
            for (int nt = 0; nt < 4; ++nt)
                acc[nt] = __builtin_amdgcn_mfma_f32_16x16x32_bf16(af, bfv[nt], acc[nt], 0, 0, 0);
        }
        asm volatile("s_waitcnt lgkmcnt(0)\n\ts_barrier" ::: "memory");
    }
    float c0 = 1.f - dt_f[0];
#pragma unroll
    for (int nt = 0; nt < 4; ++nt) {
        int col_l = nt * 16 + l15;
        float bv = bias_f[bn + col_l];
#pragma unroll
        for (int r = 0; r < 4; ++r) {
            int row_l = wm + quad * 4 + r;
            float t = fmaxf(acc[nt][r] + bv, 0.f);
            basep[(size_t)(bm + row_l) * C_DIM + bn + col_l] = c0 * t;
            lT[col_l * 64 + row_l] = f2b(t * s_row[row_l]);
        }
    }
    __syncthreads();
    // coalesced transposed store: thread -> (col_l = tid>>2, 16-row segment = tid&3)
    int col_l = tid >> 2, seg = tid & 3;
    uint4 w0 = *(const uint4*)&lT[col_l * 64 + seg * 16];
    uint4 w1 = *(const uint4*)&lT[col_l * 64 + seg * 16 + 8];
    u16* dst = TsT + (size_t)(bn + col_l) * N_NODES + bm + seg * 16;
    *(uint4*)dst = w0;
    *(uint4*)(dst + 8) = w1;
}

// ================= K3: gemm2 split-K=4 raw-P [0,512) | dvec partials [512,640) =========
// gemm: 128x128 tile, BK=64, 32KB single buffer, slot-XOR swizzle, XCD-aware remap.
// Accumulates RAW P into Pacc2 (atomic); 1/d scale deferred to k5.
// dvec blocks: d partials from same (L2-resident) A panels, atomic into dvraw.
__global__ __launch_bounds__(256) void k3_gemm2(const void* __restrict__ adjraw,
        const int* __restrict__ modep,
        const u16* __restrict__ adjb, const u16* __restrict__ TsT,
        const float* __restrict__ s,
        float* __restrict__ Pacc2, float* __restrict__ dvraw) {
    __shared__ __align__(16) u16 lA[8192];   // 16 KB
    __shared__ __align__(16) u16 lB[8192];   // 16 KB
    int mode = *modep;
    const u16* A = mode ? adjb : (const u16*)adjraw;
    int tid = threadIdx.x;
    // XCD-aware remap: 640 blocks, 8 XCDs. xcd = id&7, local = id>>3 in [0,80).
    // local<64: gemm (bm = xcd*4 + local>>4, bn = (local>>2)&3, z = local&3)
    // local>=64: dvec (bm = xcd*4 + (local-64)>>2, z = (local-64)&3)
    int id = blockIdx.x;
    int xcd = id & 7, local = id >> 3;
    if (local < 64) {
        int lane = tid & 63, wave = tid >> 6;
        int bm128 = (xcd * 4 + (local >> 4)) * 128;
        int bn128 = ((local >> 2) & 3) * 128;
        int kbase = (local & 3) * KCHUNK;
        int wm = (wave & 1) * 64, wn = (wave >> 1) * 64;
        int quad = lane >> 4, l15 = lane & 15;
        int trow = tid >> 3;                       // 0..31
        int xslot = (tid & 7) ^ (trow & 7);        // inverse-swizzled global slot

        const u16* Ap[4]; const u16* Bp[4];
#pragma unroll
        for (int i = 0; i < 4; ++i) {
            Ap[i] = A   + (size_t)(bm128 + i * 32 + trow) * N_NODES + kbase + xslot * 8;
            Bp[i] = TsT + (size_t)(bn128 + i * 32 + trow) * N_NODES + kbase + xslot * 8;
        }

        f32x4 acc[4][4];
#pragma unroll
        for (int a = 0; a < 4; ++a)
#pragma unroll
            for (int b = 0; b < 4; ++b) acc[a][b] = (f32x4){0.f, 0.f, 0.f, 0.f};

        for (int k0 = 0; k0 < KCHUNK; k0 += 64) {
#pragma unroll
            for (int i = 0; i < 4; ++i) gload16(Ap[i] + k0, lA + i * 2048 + tid * 8);
#pragma unroll
            for (int i = 0; i < 4; ++i) gload16(Bp[i] + k0, lB + i * 2048 + tid * 8);
            asm volatile("s_waitcnt vmcnt(0)\n\ts_barrier" ::: "memory");
            __builtin_amdgcn_sched_barrier(0);
#pragma unroll
            for (int kk = 0; kk < 2; ++kk) {
                int xr = (((kk << 2) | quad) ^ (l15 & 7)) * 8;
                bf16x8 af[4], bfv[4];
#pragma unroll
                for (int mt = 0; mt < 4; ++mt) af[mt] = *(const bf16x8*)&lA[(wm + mt * 16 + l15) * 64 + xr];
#pragma unroll
                for (int nt = 0; nt < 4; ++nt) bfv[nt] = *(const bf16x8*)&lB[(wn + nt * 16 + l15) * 64 + xr];
#pragma unroll
                for (int mt = 0; mt < 4; ++mt)
#pragma unroll
                    for (int nt = 0; nt < 4; ++nt)
                        acc[mt][nt] = __builtin_amdgcn_mfma_f32_16x16x32_bf16(af[mt], bfv[nt], acc[mt][nt], 0, 0, 0);
            }
            asm volatile("s_waitcnt lgkmcnt(0)\n\ts_barrier" ::: "memory");
        }

#pragma unroll
        for (int mt = 0; mt < 4; ++mt) {
#pragma unroll
            for (int nt = 0; nt < 4; ++nt) {
                int col = bn128 + wn + nt * 16 + l15;
#pragma unroll
                for (int r = 0; r < 4; ++r) {
                    int row = bm128 + wm + mt * 16 + quad * 4 + r;
                    atomicAdd(&Pacc2[(size_t)row * C_DIM + col], acc[mt][nt][r]);
                }
            }
        }
    } else {
        // dvec partial: rows [bm128, +128), k in [kbase, +1024). A panel is L2-hot.
        int l2 = local - 64;
        int bm128 = (xcd * 4 + (l2 >> 2)) * 128;
        int kbase = (l2 & 3) * KCHUNK;
        float* s_lds = (float*)lA;               // 4 KB
        ((float4*)s_lds)[tid] = ((const float4*)(s + kbase))[tid];
        __syncthreads();
        int lane = tid & 63, wave = tid >> 6;
        const u16* base_row = A + (size_t)(bm128 + wave * 32) * N_NODES + kbase;
        for (int r = 0; r < 32; ++r) {
            const u16x8* rp = (const u16x8*)(base_row + (size_t)r * N_NODES) + lane;
            float acc = 0.f;
#pragma unroll
            for (int it = 0; it < 2; ++it) {
                u16x8 v = rp[it * 64];
                const float* sp = s_lds + it * 512 + lane * 8;
#pragma unroll
                for (int e = 0; e < 8; ++e) acc += b2f(v[e]) * sp[e];
            }
#pragma unroll
            for (int off = 32; off > 0; off >>= 1) acc += __shfl_down(acc, off);
            if (lane == 0) atomicAdd(&dvraw[bm128 + wave * 32 + r], acc);
        }
    }
}

// ================= K5: finalize both modes: out = base + (dt/EPS)*P/(d+1e-5) ============
__global__ __launch_bounds__(256) void k5_fin(const int* __restrict__ modep,
                                              const float* __restrict__ dt_f,
                                              const float* __restrict__ Pacc2,
                                              const float* __restrict__ dvraw,
                                              const float* __restrict__ Pacc_base,
                                              void* __restrict__ out) {
    int mode = *modep;
    int idx = blockIdx.x * 256 + threadIdx.x;          // f32x4 granularity, 524288 total
    float c1 = dt_f[0] * 4.f;                          // dt / EPS
    const float4* basep = mode ? (const float4*)out : (const float4*)Pacc_base;
    float4 b = basep[idx];
    float4 p = ((const float4*)Pacc2)[idx];
    int row = idx >> 7;                                // (idx*4)/512
    float rscale = c1 / (dvraw[row] + 1e-5f);
    float4 v;
    v.x = b.x + p.x * rscale;
    v.y = b.y + p.y * rscale;
    v.z = b.z + p.z * rscale;
    v.w = b.w + p.w * rscale;
    if (mode) {
        ((float4*)out)[idx] = v;
    } else {
        ushort4 o; o.x = f2b(v.x); o.y = f2b(v.y); o.z = f2b(v.z); o.w = f2b(v.w);
        ((ushort4*)out)[idx] = o;
    }
}

extern "C" void kernel_launch(void* const* d_in, const int* in_sizes, int n_in,
                              void* d_out, int out_size, void* d_ws, size_t ws_size,
                              hipStream_t stream) {
    const void* x   = d_in[0];
    const void* adj = d_in[1];
    const void* Wp  = d_in[2];
    const void* bp  = d_in[3];
    const void* Wp1 = d_in[4];
    const void* bp1 = d_in[5];
    const void* Wp2 = d_in[6];
    const void* bp2 = d_in[7];
    const void* Wf  = d_in[8];
    const void* bfc = d_in[9];
    const void* dtp = d_in[10];

    char* ws = (char*)d_ws;
    int*   modep  = (int*)(ws + OFF_MODE);
    float* dt_f   = (float*)(ws + OFF_DT);
    float* bias_f = (float*)(ws + OFF_BIAS);
    float* bp_f   = (float*)(ws + OFF_BP);
    float* bp1_f  = (float*)(ws + OFF_BP1);
    float* Wp2_f  = (float*)(ws + OFF_WP2);
    float* bp2_f  = (float*)(ws + OFF_BP2);
    float* q      = (float*)(ws + OFF_Q);
    float* s      = (float*)(ws + OFF_S);
    float* dvraw  = (float*)(ws + OFF_DV);
    u32*   WpP    = (u32*)(ws + OFF_WPP);
    u32*   Wp1P   = (u32*)(ws + OFF_WP1P);
    u16*   WfT    = (u16*)(ws + OFF_WFT);
    float* Pacc2  = (float*)(ws + OFF_PACC);
    u16*   TsT    = (u16*)(ws + OFF_TST);
    u16*   xb     = (u16*)(ws + OFF_XB);
    u16*   adjb   = (u16*)(ws + OFF_ADJB);
    float* Pacc_base = (float*)(ws + OFF_ADJB);   // bf16 mode only: adjb unused there

    k1_prep<<<5527, 256, 0, stream>>>(adj, x, Wp, bp, Wp1, bp1, Wp2, bp2, Wf, bfc, dtp,
                                      modep, bp_f, bp1_f, Wp2_f, bp2_f, bias_f, dt_f,
                                      WpP, Wp1P, adjb, q, xb, WfT, Pacc2, dvraw);
    k1p_pi<<<512, 256, 0, stream>>>(x, modep, xb, WpP, Wp1P, bp_f, bp1_f, Wp2_f, bp2_f, q, s);
    k2_gemm1<<<512, 256, 0, stream>>>(x, modep, s, bias_f, dt_f, xb, WfT, TsT, d_out, Pacc_base);
    k3_gemm2<<<640, 256, 0, stream>>>(adj, modep, adjb, TsT, s, Pacc2, dvraw);
    k5_fin<<<2048, 256, 0, stream>>>(modep, dt_f, Pacc2, dvraw, Pacc_base, d_out);
}

// Round 6
// 225.458 us; speedup vs baseline: 1.0652x; 1.0402x over previous
//
#include <hip/hip_runtime.h>
#include <hip/hip_bf16.h>

#define N_NODES 4096
#define C_DIM   512
#define L_DIM   64
#define SPLITS  4
#define KCHUNK  (N_NODES / SPLITS)   // 1024

typedef unsigned short u16;
typedef unsigned int   u32;
using bf16x8 = __attribute__((ext_vector_type(8))) __bf16;
using u16x8  = __attribute__((ext_vector_type(8))) unsigned short;
using f32x4  = __attribute__((ext_vector_type(4))) float;

__device__ __forceinline__ float b2f(u16 u) {
    union { unsigned int i; float f; } v; v.i = ((unsigned int)u) << 16; return v.f;
}
__device__ __forceinline__ u16 f2b(float f) {
    __bf16 h = (__bf16)f;                 // RNE
    union { __bf16 h; u16 u; } v; v.h = h; return v.u;
}
__device__ __forceinline__ void gload16(const void* g, void* l) {
    __builtin_amdgcn_global_load_lds((const __attribute__((address_space(1))) void*)g,
                                     (__attribute__((address_space(3))) void*)l,
                                     16, 0, 0);
}
// mode: 0 = bf16 inputs, 1 = f32. adj ~ U[0,1): bf16 u16 <= 0x3F80; f32 low-halves random.
__device__ __forceinline__ int detect_mode_inl(const u16* __restrict__ adj) {
    int m = 0;
#pragma unroll
    for (int i = 0; i < 64; ++i) m |= (adj[i] >= 0x8000) ? 1 : 0;
    return m;
}
__device__ __forceinline__ float ldin(const void* p, int i, int mode) {
    if (mode) return ((const float*)p)[i];
    return b2f(((const u16*)p)[i]);
}

// ---- workspace byte offsets ----
#define OFF_MODE  0
#define OFF_DT    64
#define OFF_BIAS  1024      // 512 f32
#define OFF_BP    4096      // 64 f32
#define OFF_BP1   4608      // 512 f32
#define OFF_WP2   8192      // 512 f32
#define OFF_BP2   10240     // 1 f32
#define OFF_Q     16384
#define OFF_S     32768
#define OFF_DV    49152     // 4096 f32: RAW d partials (memset by launcher)
#define OFF_WPP   65536     // 16384 u32: packed bf16 k-pairs of Wp
#define OFF_WP1P  131072    // 16384 u32: packed bf16 k-pairs of Wp1
#define OFF_WFT   196608    // 512 KB bf16 Wf^T -> ends 720896
#define OFF_PACC  720896    // 8 MB f32: raw P accumulator (memset by launcher)
#define OFF_TST   9437184   // 4 MB bf16 TsT[c][j] = s[j]*target[j][c]
#define OFF_XB    13631488  // 4 MB bf16 x
#define OFF_ADJB  17825792  // 32 MB bf16 adj (f32 mode); first 8MB doubles as f32 base (bf16 mode)

// ================= K1: rowsum [0,1024) | x->bf16 [1024,1152) | Wf^T [1152,1408) |
//   packWp [1408,1416) | packWp1 [1416,1424) | smalls [1424,1431) ====
__global__ __launch_bounds__(256) void k1_prep(const void* __restrict__ adj, const void* __restrict__ x,
        const void* Wp, const void* bp, const void* Wp1, const void* bp1,
        const void* Wp2, const void* bp2, const void* Wf, const void* bfc, const void* dt,
        int* __restrict__ modep,
        float* __restrict__ bp_f, float* __restrict__ bp1_f,
        float* __restrict__ Wp2_f, float* __restrict__ bp2_f,
        float* __restrict__ bias_f, float* __restrict__ dt_f,
        u32* __restrict__ WpP, u32* __restrict__ Wp1P,
        u16* __restrict__ adjb, float* __restrict__ q, u16* __restrict__ xb,
        u16* __restrict__ WfT) {
    __shared__ float tile[32][33];
    int bid = blockIdx.x, tid = threadIdx.x;
    int mode = detect_mode_inl((const u16*)adj);
    if (bid < 1024) {
        // rowsum (+bf16 copy in f32 mode)
        int wave = tid >> 6, lane = tid & 63;
        int row = bid * 4 + wave;
        float acc = 0.f;
        if (mode) {
            const float4* rp = (const float4*)((const float*)adj + (size_t)row * N_NODES);
            ushort4* wp = (ushort4*)(adjb + (size_t)row * N_NODES);
#pragma unroll 8
            for (int it = 0; it < 16; ++it) {
                float4 v = rp[it * 64 + lane];
                acc += (v.x + v.y) + (v.z + v.w);
                ushort4 o; o.x = f2b(v.x); o.y = f2b(v.y); o.z = f2b(v.z); o.w = f2b(v.w);
                wp[it * 64 + lane] = o;
            }
        } else {
            const u16x8* rp = (const u16x8*)((const u16*)adj + (size_t)row * N_NODES);
#pragma unroll
            for (int it = 0; it < 8; ++it) {
                u16x8 v = rp[it * 64 + lane];
#pragma unroll
                for (int e = 0; e < 8; ++e) acc += b2f(v[e]);
            }
        }
#pragma unroll
        for (int off = 32; off > 0; off >>= 1) acc += __shfl_down(acc, off);
        if (lane == 0) q[row] = acc;
    } else if (bid < 1152) {
        if (mode == 0) return;
        // x -> bf16: 128 blocks x 256 threads x 16 float4 = 8 MB
        int base = (bid - 1024) * 256 + tid;
#pragma unroll
        for (int i = 0; i < 16; ++i) {
            int idx = i * 32768 + base;
            float4 v = ((const float4*)x)[idx];
            ushort4 o; o.x = f2b(v.x); o.y = f2b(v.y); o.z = f2b(v.z); o.w = f2b(v.w);
            ((ushort4*)xb)[idx] = o;
        }
    } else if (bid < 1408) {
        int g = bid - 1152;
        int tx = tid & 31, ty = tid >> 5;
        int x0 = (g & 15) * 32, y0 = (g >> 4) * 32;
        if (mode) {
            const float* src = (const float*)Wf;
#pragma unroll
            for (int r = ty; r < 32; r += 8) tile[r][tx] = src[(size_t)(y0 + r) * C_DIM + x0 + tx];
        } else {
            const u16* src = (const u16*)Wf;
#pragma unroll
            for (int r = ty; r < 32; r += 8) tile[r][tx] = b2f(src[(size_t)(y0 + r) * C_DIM + x0 + tx]);
        }
        __syncthreads();
#pragma unroll
        for (int r = ty; r < 32; r += 8)
            WfT[(size_t)(x0 + r) * C_DIM + y0 + tx] = f2b(tile[tx][r]);
    } else if (bid < 1416) {
        // WpP[k2*64 + j] = pack(Wp[2k2][j], Wp[2k2+1][j]); 8 blocks x 2048
        int base = (bid - 1408) * 2048 + tid;
#pragma unroll
        for (int i = 0; i < 8; ++i) {
            int idx = base + i * 256;                    // 0..16383
            int k2i = idx >> 6, j = idx & 63;
            float a = ldin(Wp, (2 * k2i) * L_DIM + j, mode);
            float b = ldin(Wp, (2 * k2i + 1) * L_DIM + j, mode);
            WpP[idx] = (u32)f2b(a) | ((u32)f2b(b) << 16);
        }
    } else if (bid < 1424) {
        // Wp1P[jj2*512 + m] = pack(Wp1[2jj2][m], Wp1[2jj2+1][m]); 8 blocks x 2048
        int base = (bid - 1416) * 2048 + tid;
#pragma unroll
        for (int i = 0; i < 8; ++i) {
            int idx = base + i * 256;                    // 0..16383
            int jj2 = idx >> 9, m = idx & 511;
            float a = ldin(Wp1, (2 * jj2) * C_DIM + m, mode);
            float b = ldin(Wp1, (2 * jj2 + 1) * C_DIM + m, mode);
            Wp1P[idx] = (u32)f2b(a) | ((u32)f2b(b) << 16);
        }
    } else {
        if (bid == 1424 && tid == 0) *modep = mode;
        int idx = (bid - 1424) * 256 + tid;
        if (idx < 64)           bp_f[idx]          = ldin(bp,  idx, mode);
        else if (idx < 576)     bp1_f[idx - 64]    = ldin(bp1, idx - 64, mode);
        else if (idx < 1088)    Wp2_f[idx - 576]   = ldin(Wp2, idx - 576, mode);
        else if (idx == 1088)   bp2_f[0]           = ldin(bp2, 0, mode);
        else if (idx < 1601)    bias_f[idx - 1089] = ldin(bfc, idx - 1089, mode);
        else if (idx == 1601)   dt_f[0]            = ldin(dt, 0, mode);
    }
}

// ================= K1p: pi-MLP (512 blocks x 8 rows), packed bf16 weights; writes s = pi/q ====
__global__ __launch_bounds__(256) void k1p_pi(const void* __restrict__ xraw,
        const int* __restrict__ modep, const u16* __restrict__ xb,
        const u32* __restrict__ WpP, const u32* __restrict__ Wp1P,
        const float* __restrict__ bp_f,  const float* __restrict__ bp1_f,
        const float* __restrict__ Wp2_f, const float* __restrict__ bp2_f,
        const float* __restrict__ q, float* __restrict__ s) {
    __shared__ __align__(16) char smem[26880];
    int bid = blockIdx.x, tid = threadIdx.x;
    int mode = *modep;
    float (*sx)[C_DIM]      = (float(*)[C_DIM])smem;                 // 16 KB
    float (*red)[8][L_DIM]  = (float(*)[8][L_DIM])(smem + 16384);    // 8 KB
    float (*sz)[L_DIM]      = (float(*)[L_DIM])(smem + 24576);       // 2 KB
    float (*rw)[8]          = (float(*)[8])(smem + 26624);           // 128 B
    int i0 = bid * 8;
    const u16* xsrc = mode ? xb : (const u16*)xraw;
    const u16x8* xp = (const u16x8*)(xsrc + (size_t)i0 * C_DIM);
#pragma unroll
    for (int r = 0; r < 2; ++r) {
        u16x8 v = xp[tid + 256 * r];
        float* dstf = &sx[0][0] + (size_t)(tid + 256 * r) * 8;
#pragma unroll
        for (int e = 0; e < 8; ++e) dstf[e] = b2f(v[e]);
    }
    __syncthreads();
    // z-phase: thread (part = tid>>6, j = tid&63) covers k in [part*128, +128)
    int j = tid & 63, part = tid >> 6;
    float za[8];
#pragma unroll
    for (int n = 0; n < 8; ++n) za[n] = 0.f;
    const u32* wp = WpP + part * 4096 + j;
#pragma unroll 8
    for (int kk = 0; kk < 64; ++kk) {
        u32 w = wp[kk * 64];
        float wa = b2f((u16)(w & 0xFFFF)), wb = b2f((u16)(w >> 16));
        int k = part * 128 + kk * 2;
#pragma unroll
        for (int n = 0; n < 8; ++n) za[n] += sx[n][k] * wa + sx[n][k + 1] * wb;
    }
#pragma unroll
    for (int n = 0; n < 8; ++n) red[part][n][j] = za[n];
    __syncthreads();
#pragma unroll
    for (int r = 0; r < 2; ++r) {
        int idx = tid + r * 256; int n = idx >> 6, jj = idx & 63;
        sz[n][jj] = red[0][n][jj] + red[1][n][jj] + red[2][n][jj] + red[3][n][jj] + bp_f[jj];
    }
    __syncthreads();
    // h-phase: thread owns m0 = tid, m1 = tid+256
    int m0 = tid, m1 = tid + 256;
    float h0[8], h1[8];
    float b0 = bp1_f[m0], b1 = bp1_f[m1];
#pragma unroll
    for (int n = 0; n < 8; ++n) { h0[n] = b0; h1[n] = b1; }
    const u32* w1p = Wp1P + m0;
#pragma unroll 4
    for (int jj2 = 0; jj2 < 32; ++jj2) {
        u32 w0 = w1p[jj2 * 512], w1 = w1p[jj2 * 512 + 256];
        float w0a = b2f((u16)(w0 & 0xFFFF)), w0b = b2f((u16)(w0 >> 16));
        float w1a = b2f((u16)(w1 & 0xFFFF)), w1b = b2f((u16)(w1 >> 16));
#pragma unroll
        for (int n = 0; n < 8; ++n) {
            float za_ = sz[n][2 * jj2], zb_ = sz[n][2 * jj2 + 1];
            h0[n] += za_ * w0a + zb_ * w0b;
            h1[n] += za_ * w1a + zb_ * w1b;
        }
    }
    float w2a = Wp2_f[m0], w2b = Wp2_f[m1];
    float p[8];
#pragma unroll
    for (int n = 0; n < 8; ++n)
        p[n] = fmaxf(h0[n], 0.f) * w2a + fmaxf(h1[n], 0.f) * w2b;
#pragma unroll
    for (int off = 32; off > 0; off >>= 1)
#pragma unroll
        for (int n = 0; n < 8; ++n) p[n] += __shfl_down(p[n], off);
    int lane = tid & 63, wave = tid >> 6;
    if (lane == 0) {
#pragma unroll
        for (int n = 0; n < 8; ++n) rw[wave][n] = p[n];
    }
    __syncthreads();
    if (tid < 8) {
        float tot = rw[0][tid] + rw[1][tid] + rw[2][tid] + rw[3][tid] + bp2_f[0];
        float pi = 1.f / (1.f + expf(-tot));
        s[i0 + tid] = pi / q[i0 + tid];
    }
}

// ================= K2: gemm1 BK=64 swizzled + fused s-scale/transpose (512 blocks) ====
// base = (1-dt)*t -> out (f32 mode) / Pacc_base (bf16 mode); TsT[col][row] = bf16(t*s[row])
__global__ __launch_bounds__(256) void k2_gemm1(const void* __restrict__ xraw,
        const int* __restrict__ modep,
        const float* __restrict__ s, const float* __restrict__ bias_f, const float* __restrict__ dt_f,
        const u16* __restrict__ xb, const u16* __restrict__ WfT,
        u16* __restrict__ TsT, void* __restrict__ out, float* __restrict__ Pacc_base) {
    __shared__ __align__(16) char smem[16640];
    int bid = blockIdx.x, tid = threadIdx.x;
    int mode = *modep;
    u16* lA = (u16*)smem;                    // 8 KB: 64 rows x 64 elem
    u16* lB = (u16*)(smem + 8192);           // 8 KB
    u16* lT = (u16*)smem;                    // 8 KB, aliases lA after main loop
    float* s_row = (float*)(smem + 16384);   // 256 B
    int lane = tid & 63, wave = tid >> 6;
    int bm = (bid & 63) * 64, bn = (bid >> 6) * 64;
    if (tid < 64) s_row[tid] = s[bm + tid];
    const u16* Axb = mode ? xb : (const u16*)xraw;
    float* basep = mode ? (float*)out : Pacc_base;
    int quad = lane >> 4, l15 = lane & 15;
    int wm = wave * 16;
    int trow = tid >> 3;                       // 0..31
    int xslot = (tid & 7) ^ (trow & 7);        // inverse-swizzled global slot
    const u16* Ap0 = Axb + (size_t)(bm + trow) * C_DIM + xslot * 8;
    const u16* Ap1 = Axb + (size_t)(bm + 32 + trow) * C_DIM + xslot * 8;
    const u16* Bp0 = WfT + (size_t)(bn + trow) * C_DIM + xslot * 8;
    const u16* Bp1 = WfT + (size_t)(bn + 32 + trow) * C_DIM + xslot * 8;
    f32x4 acc[4];
#pragma unroll
    for (int nt = 0; nt < 4; ++nt) acc[nt] = (f32x4){0.f, 0.f, 0.f, 0.f};
    for (int k0 = 0; k0 < C_DIM; k0 += 64) {
        gload16(Ap0 + k0, lA + tid * 8);
        gload16(Ap1 + k0, lA + 2048 + tid * 8);
        gload16(Bp0 + k0, lB + tid * 8);
        gload16(Bp1 + k0, lB + 2048 + tid * 8);
        __syncthreads();
#pragma unroll
        for (int kk = 0; kk < 2; ++kk) {
            int xr = (((kk << 2) | quad) ^ (l15 & 7)) * 8;
            bf16x8 af = *(const bf16x8*)&lA[(wm + l15) * 64 + xr];
            bf16x8 bfv[4];
#pragma unroll
            for (int nt = 0; nt < 4; ++nt)
                bfv[nt] = *(const bf16x8*)&lB[(nt * 16 + l15) * 64 + xr];
#pragma unroll
            for (int nt = 0; nt < 4; ++nt)
                acc[nt] = __builtin_amdgcn_mfma_f32_16x16x32_bf16(af, bfv[nt], acc[nt], 0, 0, 0);
        }
        __syncthreads();
    }
    float c0 = 1.f - dt_f[0];
#pragma unroll
    for (int nt = 0; nt < 4; ++nt) {
        int col_l = nt * 16 + l15;
        float bv = bias_f[bn + col_l];
#pragma unroll
        for (int r = 0; r < 4; ++r) {
            int row_l = wm + quad * 4 + r;
            float t = fmaxf(acc[nt][r] + bv, 0.f);
            basep[(size_t)(bm + row_l) * C_DIM + bn + col_l] = c0 * t;
            lT[col_l * 64 + row_l] = f2b(t * s_row[row_l]);
        }
    }
    __syncthreads();
    // coalesced transposed store: thread -> (col_l = tid>>2, 16-row segment = tid&3)
    int col_l = tid >> 2, seg = tid & 3;
    uint4 w0 = *(const uint4*)&lT[col_l * 64 + seg * 16];
    uint4 w1 = *(const uint4*)&lT[col_l * 64 + seg * 16 + 8];
    u16* dst = TsT + (size_t)(bn + col_l) * N_NODES + bm + seg * 16;
    *(uint4*)dst = w0;
    *(uint4*)(dst + 8) = w1;
}

// ================= K3: gemm2 (exact R0 structure) + fused dvec-via-MFMA ================
// 128x128 tile, BK=64 (two 32-k subtiles, [row][32] LDS), dim3(32,4,SPLITS).
// Raw P partials atomically accumulated into Pacc2; d partials (B-col = s) into dvraw.
__global__ __launch_bounds__(256) void k3_gemm2(const void* __restrict__ adjraw,
        const int* __restrict__ modep,
        const u16* __restrict__ adjb, const u16* __restrict__ TsT,
        const float* __restrict__ s,
        float* __restrict__ Pacc2, float* __restrict__ dvraw) {
    __shared__ __align__(16) u16 lA[8192];   // 16 KB: [0..4095] k-sub 0, [4096..8191] k-sub 1
    __shared__ __align__(16) u16 lB[8192];   // 16 KB
    __shared__ __align__(16) u16 s_s[1024];  // 2 KB: bf16(s) for this k-chunk
    int mode = *modep;
    const u16* A = mode ? adjb : (const u16*)adjraw;
    int tid = threadIdx.x;
    int lane = tid & 63, wave = tid >> 6;
    int bm = blockIdx.x * 128, bn = blockIdx.y * 128;
    int kbase = blockIdx.z * KCHUNK;
    int wm = (wave & 1) * 64, wn = (wave >> 1) * 64;
    int quad = lane >> 4, l15 = lane & 15;
    bool do_d = (blockIdx.y == 0) && (wave < 2);   // waves 0,1 (wn==0) of bn==0 blocks

#pragma unroll
    for (int i = 0; i < 4; ++i) {
        int k = tid + i * 256;
        s_s[k] = f2b(s[kbase + k]);
    }

    const u16* Ab0 = A + (size_t)(bm + (tid >> 2)) * N_NODES + kbase + (tid & 3) * 8;
    const u16* Ab1 = A + (size_t)(bm + 64 + (tid >> 2)) * N_NODES + kbase + (tid & 3) * 8;
    const u16* Bb0 = TsT + (size_t)(bn + (tid >> 2)) * N_NODES + kbase + (tid & 3) * 8;
    const u16* Bb1 = TsT + (size_t)(bn + 64 + (tid >> 2)) * N_NODES + kbase + (tid & 3) * 8;
    u16* la00 = lA + tid * 8;        u16* la01 = lA + 2048 + tid * 8;   // k-sub 0
    u16* la10 = lA + 4096 + tid * 8; u16* la11 = lA + 6144 + tid * 8;   // k-sub 1
    u16* lb00 = lB + tid * 8;        u16* lb01 = lB + 2048 + tid * 8;
    u16* lb10 = lB + 4096 + tid * 8; u16* lb11 = lB + 6144 + tid * 8;

    f32x4 acc[4][4];
#pragma unroll
    for (int a = 0; a < 4; ++a)
#pragma unroll
        for (int b = 0; b < 4; ++b) acc[a][b] = (f32x4){0.f, 0.f, 0.f, 0.f};
    f32x4 accd[4];
#pragma unroll
    for (int a = 0; a < 4; ++a) accd[a] = (f32x4){0.f, 0.f, 0.f, 0.f};
    u16 dmask = (l15 == 0) ? (u16)0xFFFFu : (u16)0;

    for (int k0 = 0; k0 < KCHUNK; k0 += 64) {
        gload16(Ab0 + k0, la00);
        gload16(Ab1 + k0, la01);
        gload16(Ab0 + k0 + 32, la10);
        gload16(Ab1 + k0 + 32, la11);
        gload16(Bb0 + k0, lb00);
        gload16(Bb1 + k0, lb01);
        gload16(Bb0 + k0 + 32, lb10);
        gload16(Bb1 + k0 + 32, lb11);
        __syncthreads();
#pragma unroll
        for (int kk = 0; kk < 2; ++kk) {
            const u16* baseA = lA + kk * 4096;
            const u16* baseB = lB + kk * 4096;
            bf16x8 af[4], bfv[4];
#pragma unroll
            for (int mt = 0; mt < 4; ++mt) af[mt] = *(const bf16x8*)&baseA[(wm + mt * 16 + l15) * 32 + quad * 8];
#pragma unroll
            for (int nt = 0; nt < 4; ++nt) bfv[nt] = *(const bf16x8*)&baseB[(wn + nt * 16 + l15) * 32 + quad * 8];
#pragma unroll
            for (int mt = 0; mt < 4; ++mt)
#pragma unroll
                for (int nt = 0; nt < 4; ++nt)
                    acc[mt][nt] = __builtin_amdgcn_mfma_f32_16x16x32_bf16(af[mt], bfv[nt], acc[mt][nt], 0, 0, 0);
            if (do_d) {
                // B_s fragment: col 0 = s[k], cols 1..15 = 0
                u16x8 su = *(const u16x8*)&s_s[k0 + kk * 32 + quad * 8];
#pragma unroll
                for (int e = 0; e < 8; ++e) su[e] &= dmask;
                bf16x8 bs = *(bf16x8*)&su;
#pragma unroll
                for (int mt = 0; mt < 4; ++mt)
                    accd[mt] = __builtin_amdgcn_mfma_f32_16x16x32_bf16(af[mt], bs, accd[mt], 0, 0, 0);
            }
        }
        __syncthreads();
    }

#pragma unroll
    for (int mt = 0; mt < 4; ++mt) {
#pragma unroll
        for (int nt = 0; nt < 4; ++nt) {
            int col = bn + wn + nt * 16 + l15;
#pragma unroll
            for (int r = 0; r < 4; ++r) {
                int row = bm + wm + mt * 16 + quad * 4 + r;
                atomicAdd(&Pacc2[(size_t)row * C_DIM + col], acc[mt][nt][r]);
            }
        }
    }
    if (do_d && l15 == 0) {
#pragma unroll
        for (int mt = 0; mt < 4; ++mt)
#pragma unroll
            for (int r = 0; r < 4; ++r)
                atomicAdd(&dvraw[bm + wm + mt * 16 + quad * 4 + r], accd[mt][r]);
    }
}

// ================= K5: finalize both modes: out = base + (dt/EPS)*P/(d+1e-5) ============
// 256 blocks x 256 threads x 8 float4
__global__ __launch_bounds__(256) void k5_fin(const int* __restrict__ modep,
                                              const float* __restrict__ dt_f,
                                              const float* __restrict__ Pacc2,
                                              const float* __restrict__ dvraw,
                                              const float* __restrict__ Pacc_base,
                                              void* __restrict__ out) {
    int mode = *modep;
    float c1 = dt_f[0] * 4.f;                          // dt / EPS
    const float4* basep = mode ? (const float4*)out : (const float4*)Pacc_base;
#pragma unroll
    for (int i = 0; i < 8; ++i) {
        int idx = blockIdx.x * 2048 + i * 256 + threadIdx.x;   // f32x4 units, 524288 total
        float4 b = basep[idx];
        float4 p = ((const float4*)Pacc2)[idx];
        int row = idx >> 7;                            // (idx*4)/512
        float rscale = c1 / (dvraw[row] + 1e-5f);
        float4 v;
        v.x = b.x + p.x * rscale;
        v.y = b.y + p.y * rscale;
        v.z = b.z + p.z * rscale;
        v.w = b.w + p.w * rscale;
        if (mode) {
            ((float4*)out)[idx] = v;
        } else {
            ushort4 o; o.x = f2b(v.x); o.y = f2b(v.y); o.z = f2b(v.z); o.w = f2b(v.w);
            ((ushort4*)out)[idx] = o;
        }
    }
}

extern "C" void kernel_launch(void* const* d_in, const int* in_sizes, int n_in,
                              void* d_out, int out_size, void* d_ws, size_t ws_size,
                              hipStream_t stream) {
    const void* x   = d_in[0];
    const void* adj = d_in[1];
    const void* Wp  = d_in[2];
    const void* bp  = d_in[3];
    const void* Wp1 = d_in[4];
    const void* bp1 = d_in[5];
    const void* Wp2 = d_in[6];
    const void* bp2 = d_in[7];
    const void* Wf  = d_in[8];
    const void* bfc = d_in[9];
    const void* dtp = d_in[10];

    char* ws = (char*)d_ws;
    int*   modep  = (int*)(ws + OFF_MODE);
    float* dt_f   = (float*)(ws + OFF_DT);
    float* bias_f = (float*)(ws + OFF_BIAS);
    float* bp_f   = (float*)(ws + OFF_BP);
    float* bp1_f  = (float*)(ws + OFF_BP1);
    float* Wp2_f  = (float*)(ws + OFF_WP2);
    float* bp2_f  = (float*)(ws + OFF_BP2);
    float* q      = (float*)(ws + OFF_Q);
    float* s      = (float*)(ws + OFF_S);
    float* dvraw  = (float*)(ws + OFF_DV);
    u32*   WpP    = (u32*)(ws + OFF_WPP);
    u32*   Wp1P   = (u32*)(ws + OFF_WP1P);
    u16*   WfT    = (u16*)(ws + OFF_WFT);
    float* Pacc2  = (float*)(ws + OFF_PACC);
    u16*   TsT    = (u16*)(ws + OFF_TST);
    u16*   xb     = (u16*)(ws + OFF_XB);
    u16*   adjb   = (u16*)(ws + OFF_ADJB);
    float* Pacc_base = (float*)(ws + OFF_ADJB);   // bf16 mode only: adjb unused there

    hipMemsetAsync(Pacc2, 0, (size_t)N_NODES * C_DIM * sizeof(float), stream);
    hipMemsetAsync(dvraw, 0, (size_t)N_NODES * sizeof(float), stream);
    k1_prep<<<1431, 256, 0, stream>>>(adj, x, Wp, bp, Wp1, bp1, Wp2, bp2, Wf, bfc, dtp,
                                      modep, bp_f, bp1_f, Wp2_f, bp2_f, bias_f, dt_f,
                                      WpP, Wp1P, adjb, q, xb, WfT);
    k1p_pi<<<512, 256, 0, stream>>>(x, modep, xb, WpP, Wp1P, bp_f, bp1_f, Wp2_f, bp2_f, q, s);
    k2_gemm1<<<512, 256, 0, stream>>>(x, modep, s, bias_f, dt_f, xb, WfT, TsT, d_out, Pacc_base);
    k3_gemm2<<<dim3(32, 4, SPLITS), 256, 0, stream>>>(adj, modep, adjb, TsT, s, Pacc2, dvraw);
    k5_fin<<<256, 256, 0, stream>>>(modep, dt_f, Pacc2, dvraw, Pacc_base, d_out);
}

// Round 7
// 220.732 us; speedup vs baseline: 1.0880x; 1.0214x over previous
//
#include <hip/hip_runtime.h>
#include <hip/hip_bf16.h>

#define N_NODES 4096
#define C_DIM   512
#define L_DIM   64
#define SPLITS  4
#define KCHUNK  (N_NODES / SPLITS)   // 1024

typedef unsigned short u16;
typedef unsigned int   u32;
using bf16x8 = __attribute__((ext_vector_type(8))) __bf16;
using u16x8  = __attribute__((ext_vector_type(8))) unsigned short;
using f32x4  = __attribute__((ext_vector_type(4))) float;

__device__ __forceinline__ float b2f(u16 u) {
    union { unsigned int i; float f; } v; v.i = ((unsigned int)u) << 16; return v.f;
}
__device__ __forceinline__ u16 f2b(float f) {
    __bf16 h = (__bf16)f;                 // RNE
    union { __bf16 h; u16 u; } v; v.h = h; return v.u;
}
__device__ __forceinline__ void gload16(const void* g, void* l) {
    __builtin_amdgcn_global_load_lds((const __attribute__((address_space(1))) void*)g,
                                     (__attribute__((address_space(3))) void*)l,
                                     16, 0, 0);
}
// mode: 0 = bf16 inputs, 1 = f32. adj ~ U[0,1): bf16 u16 <= 0x3F80; f32 low-halves random.
__device__ __forceinline__ int detect_mode_inl(const u16* __restrict__ adj) {
    int m = 0;
#pragma unroll
    for (int i = 0; i < 64; ++i) m |= (adj[i] >= 0x8000) ? 1 : 0;
    return m;
}
__device__ __forceinline__ float ldin(const void* p, int i, int mode) {
    if (mode) return ((const float*)p)[i];
    return b2f(((const u16*)p)[i]);
}

// ---- workspace byte offsets ----
#define OFF_MODE  0
#define OFF_DT    64
#define OFF_BIAS  1024      // 512 f32
#define OFF_BP    4096      // 64 f32
#define OFF_BP1   4608      // 512 f32
#define OFF_WP2   8192      // 512 f32
#define OFF_BP2   10240     // 1 f32
#define OFF_Q     16384
#define OFF_S     32768
#define OFF_DV    49152     // 4096 f32: RAW d partials (memset by launcher)
#define OFF_WPP   65536     // 16384 u32: packed bf16 k-pairs of Wp
#define OFF_WP1P  131072    // 16384 u32: packed bf16 k-pairs of Wp1
#define OFF_WFT   196608    // 512 KB bf16 Wf^T -> ends 720896
#define OFF_PACC  720896    // 8 MB f32: raw P accumulator (memset by launcher)
#define OFF_TST   9437184   // 4 MB bf16 TsT[c][j] = s[j]*target[j][c]
#define OFF_XB    13631488  // 4 MB bf16 x
#define OFF_ADJB  17825792  // 32 MB bf16 adj (f32 mode); first 8MB doubles as f32 base (bf16 mode)

// ================= K1: rowsum [0,1024) | x->bf16 [1024,1152) | Wf^T [1152,1408) |
//   packWp [1408,1416) | packWp1 [1416,1424) | smalls [1424,1431) ====
__global__ __launch_bounds__(256) void k1_prep(const void* __restrict__ adj, const void* __restrict__ x,
        const void* Wp, const void* bp, const void* Wp1, const void* bp1,
        const void* Wp2, const void* bp2, const void* Wf, const void* bfc, const void* dt,
        int* __restrict__ modep,
        float* __restrict__ bp_f, float* __restrict__ bp1_f,
        float* __restrict__ Wp2_f, float* __restrict__ bp2_f,
        float* __restrict__ bias_f, float* __restrict__ dt_f,
        u32* __restrict__ WpP, u32* __restrict__ Wp1P,
        u16* __restrict__ adjb, float* __restrict__ q, u16* __restrict__ xb,
        u16* __restrict__ WfT) {
    __shared__ float tile[32][33];
    int bid = blockIdx.x, tid = threadIdx.x;
    int mode = detect_mode_inl((const u16*)adj);
    if (bid < 1024) {
        // rowsum (+bf16 copy in f32 mode)
        int wave = tid >> 6, lane = tid & 63;
        int row = bid * 4 + wave;
        float acc = 0.f;
        if (mode) {
            const float4* rp = (const float4*)((const float*)adj + (size_t)row * N_NODES);
            ushort4* wp = (ushort4*)(adjb + (size_t)row * N_NODES);
#pragma unroll 8
            for (int it = 0; it < 16; ++it) {
                float4 v = rp[it * 64 + lane];
                acc += (v.x + v.y) + (v.z + v.w);
                ushort4 o; o.x = f2b(v.x); o.y = f2b(v.y); o.z = f2b(v.z); o.w = f2b(v.w);
                wp[it * 64 + lane] = o;
            }
        } else {
            const u16x8* rp = (const u16x8*)((const u16*)adj + (size_t)row * N_NODES);
#pragma unroll
            for (int it = 0; it < 8; ++it) {
                u16x8 v = rp[it * 64 + lane];
#pragma unroll
                for (int e = 0; e < 8; ++e) acc += b2f(v[e]);
            }
        }
#pragma unroll
        for (int off = 32; off > 0; off >>= 1) acc += __shfl_down(acc, off);
        if (lane == 0) q[row] = acc;
    } else if (bid < 1152) {
        if (mode == 0) return;
        // x -> bf16: 128 blocks x 256 threads x 16 float4 = 8 MB
        int base = (bid - 1024) * 256 + tid;
#pragma unroll
        for (int i = 0; i < 16; ++i) {
            int idx = i * 32768 + base;
            float4 v = ((const float4*)x)[idx];
            ushort4 o; o.x = f2b(v.x); o.y = f2b(v.y); o.z = f2b(v.z); o.w = f2b(v.w);
            ((ushort4*)xb)[idx] = o;
        }
    } else if (bid < 1408) {
        int g = bid - 1152;
        int tx = tid & 31, ty = tid >> 5;
        int x0 = (g & 15) * 32, y0 = (g >> 4) * 32;
        if (mode) {
            const float* src = (const float*)Wf;
#pragma unroll
            for (int r = ty; r < 32; r += 8) tile[r][tx] = src[(size_t)(y0 + r) * C_DIM + x0 + tx];
        } else {
            const u16* src = (const u16*)Wf;
#pragma unroll
            for (int r = ty; r < 32; r += 8) tile[r][tx] = b2f(src[(size_t)(y0 + r) * C_DIM + x0 + tx]);
        }
        __syncthreads();
#pragma unroll
        for (int r = ty; r < 32; r += 8)
            WfT[(size_t)(x0 + r) * C_DIM + y0 + tx] = f2b(tile[tx][r]);
    } else if (bid < 1416) {
        // WpP[k2*64 + j] = pack(Wp[2k2][j], Wp[2k2+1][j]); 8 blocks x 2048
        int base = (bid - 1408) * 2048 + tid;
#pragma unroll
        for (int i = 0; i < 8; ++i) {
            int idx = base + i * 256;                    // 0..16383
            int k2i = idx >> 6, j = idx & 63;
            float a = ldin(Wp, (2 * k2i) * L_DIM + j, mode);
            float b = ldin(Wp, (2 * k2i + 1) * L_DIM + j, mode);
            WpP[idx] = (u32)f2b(a) | ((u32)f2b(b) << 16);
        }
    } else if (bid < 1424) {
        // Wp1P[jj2*512 + m] = pack(Wp1[2jj2][m], Wp1[2jj2+1][m]); 8 blocks x 2048
        int base = (bid - 1416) * 2048 + tid;
#pragma unroll
        for (int i = 0; i < 8; ++i) {
            int idx = base + i * 256;                    // 0..16383
            int jj2 = idx >> 9, m = idx & 511;
            float a = ldin(Wp1, (2 * jj2) * C_DIM + m, mode);
            float b = ldin(Wp1, (2 * jj2 + 1) * C_DIM + m, mode);
            Wp1P[idx] = (u32)f2b(a) | ((u32)f2b(b) << 16);
        }
    } else {
        if (bid == 1424 && tid == 0) *modep = mode;
        int idx = (bid - 1424) * 256 + tid;
        if (idx < 64)           bp_f[idx]          = ldin(bp,  idx, mode);
        else if (idx < 576)     bp1_f[idx - 64]    = ldin(bp1, idx - 64, mode);
        else if (idx < 1088)    Wp2_f[idx - 576]   = ldin(Wp2, idx - 576, mode);
        else if (idx == 1088)   bp2_f[0]           = ldin(bp2, 0, mode);
        else if (idx < 1601)    bias_f[idx - 1089] = ldin(bfc, idx - 1089, mode);
        else if (idx == 1601)   dt_f[0]            = ldin(dt, 0, mode);
    }
}

// ================= K1p: pi-MLP (512 blocks x 8 rows), packed bf16 weights; writes s = pi/q ====
__global__ __launch_bounds__(256) void k1p_pi(const void* __restrict__ xraw,
        const int* __restrict__ modep, const u16* __restrict__ xb,
        const u32* __restrict__ WpP, const u32* __restrict__ Wp1P,
        const float* __restrict__ bp_f,  const float* __restrict__ bp1_f,
        const float* __restrict__ Wp2_f, const float* __restrict__ bp2_f,
        const float* __restrict__ q, float* __restrict__ s) {
    __shared__ __align__(16) char smem[26880];
    int bid = blockIdx.x, tid = threadIdx.x;
    int mode = *modep;
    float (*sx)[C_DIM]      = (float(*)[C_DIM])smem;                 // 16 KB
    float (*red)[8][L_DIM]  = (float(*)[8][L_DIM])(smem + 16384);    // 8 KB
    float (*sz)[L_DIM]      = (float(*)[L_DIM])(smem + 24576);       // 2 KB
    float (*rw)[8]          = (float(*)[8])(smem + 26624);           // 128 B
    int i0 = bid * 8;
    const u16* xsrc = mode ? xb : (const u16*)xraw;
    const u16x8* xp = (const u16x8*)(xsrc + (size_t)i0 * C_DIM);
#pragma unroll
    for (int r = 0; r < 2; ++r) {
        u16x8 v = xp[tid + 256 * r];
        float* dstf = &sx[0][0] + (size_t)(tid + 256 * r) * 8;
#pragma unroll
        for (int e = 0; e < 8; ++e) dstf[e] = b2f(v[e]);
    }
    __syncthreads();
    // z-phase: thread (part = tid>>6, j = tid&63) covers k in [part*128, +128)
    int j = tid & 63, part = tid >> 6;
    float za[8];
#pragma unroll
    for (int n = 0; n < 8; ++n) za[n] = 0.f;
    const u32* wp = WpP + part * 4096 + j;
#pragma unroll 8
    for (int kk = 0; kk < 64; ++kk) {
        u32 w = wp[kk * 64];
        float wa = b2f((u16)(w & 0xFFFF)), wb = b2f((u16)(w >> 16));
        int k = part * 128 + kk * 2;
#pragma unroll
        for (int n = 0; n < 8; ++n) za[n] += sx[n][k] * wa + sx[n][k + 1] * wb;
    }
#pragma unroll
    for (int n = 0; n < 8; ++n) red[part][n][j] = za[n];
    __syncthreads();
#pragma unroll
    for (int r = 0; r < 2; ++r) {
        int idx = tid + r * 256; int n = idx >> 6, jj = idx & 63;
        sz[n][jj] = red[0][n][jj] + red[1][n][jj] + red[2][n][jj] + red[3][n][jj] + bp_f[jj];
    }
    __syncthreads();
    // h-phase: thread owns m0 = tid, m1 = tid+256
    int m0 = tid, m1 = tid + 256;
    float h0[8], h1[8];
    float b0 = bp1_f[m0], b1 = bp1_f[m1];
#pragma unroll
    for (int n = 0; n < 8; ++n) { h0[n] = b0; h1[n] = b1; }
    const u32* w1p = Wp1P + m0;
#pragma unroll 4
    for (int jj2 = 0; jj2 < 32; ++jj2) {
        u32 w0 = w1p[jj2 * 512], w1 = w1p[jj2 * 512 + 256];
        float w0a = b2f((u16)(w0 & 0xFFFF)), w0b = b2f((u16)(w0 >> 16));
        float w1a = b2f((u16)(w1 & 0xFFFF)), w1b = b2f((u16)(w1 >> 16));
#pragma unroll
        for (int n = 0; n < 8; ++n) {
            float za_ = sz[n][2 * jj2], zb_ = sz[n][2 * jj2 + 1];
            h0[n] += za_ * w0a + zb_ * w0b;
            h1[n] += za_ * w1a + zb_ * w1b;
        }
    }
    float w2a = Wp2_f[m0], w2b = Wp2_f[m1];
    float p[8];
#pragma unroll
    for (int n = 0; n < 8; ++n)
        p[n] = fmaxf(h0[n], 0.f) * w2a + fmaxf(h1[n], 0.f) * w2b;
#pragma unroll
    for (int off = 32; off > 0; off >>= 1)
#pragma unroll
        for (int n = 0; n < 8; ++n) p[n] += __shfl_down(p[n], off);
    int lane = tid & 63, wave = tid >> 6;
    if (lane == 0) {
#pragma unroll
        for (int n = 0; n < 8; ++n) rw[wave][n] = p[n];
    }
    __syncthreads();
    if (tid < 8) {
        float tot = rw[0][tid] + rw[1][tid] + rw[2][tid] + rw[3][tid] + bp2_f[0];
        float pi = 1.f / (1.f + expf(-tot));
        s[i0 + tid] = pi / q[i0 + tid];
    }
}

// ================= K2: gemm1 BK=64 swizzled + fused s-scale/transpose (512 blocks) ====
// base = (1-dt)*t -> out (f32 mode) / Pacc_base (bf16 mode); TsT[col][row] = bf16(t*s[row])
__global__ __launch_bounds__(256) void k2_gemm1(const void* __restrict__ xraw,
        const int* __restrict__ modep,
        const float* __restrict__ s, const float* __restrict__ bias_f, const float* __restrict__ dt_f,
        const u16* __restrict__ xb, const u16* __restrict__ WfT,
        u16* __restrict__ TsT, void* __restrict__ out, float* __restrict__ Pacc_base) {
    __shared__ __align__(16) char smem[16640];
    int bid = blockIdx.x, tid = threadIdx.x;
    int mode = *modep;
    u16* lA = (u16*)smem;                    // 8 KB: 64 rows x 64 elem
    u16* lB = (u16*)(smem + 8192);           // 8 KB
    u16* lT = (u16*)smem;                    // 8 KB, aliases lA after main loop
    float* s_row = (float*)(smem + 16384);   // 256 B
    int lane = tid & 63, wave = tid >> 6;
    int bm = (bid & 63) * 64, bn = (bid >> 6) * 64;
    if (tid < 64) s_row[tid] = s[bm + tid];
    const u16* Axb = mode ? xb : (const u16*)xraw;
    float* basep = mode ? (float*)out : Pacc_base;
    int quad = lane >> 4, l15 = lane & 15;
    int wm = wave * 16;
    int trow = tid >> 3;                       // 0..31
    int xslot = (tid & 7) ^ (trow & 7);        // inverse-swizzled global slot
    const u16* Ap0 = Axb + (size_t)(bm + trow) * C_DIM + xslot * 8;
    const u16* Ap1 = Axb + (size_t)(bm + 32 + trow) * C_DIM + xslot * 8;
    const u16* Bp0 = WfT + (size_t)(bn + trow) * C_DIM + xslot * 8;
    const u16* Bp1 = WfT + (size_t)(bn + 32 + trow) * C_DIM + xslot * 8;
    f32x4 acc[4];
#pragma unroll
    for (int nt = 0; nt < 4; ++nt) acc[nt] = (f32x4){0.f, 0.f, 0.f, 0.f};
    for (int k0 = 0; k0 < C_DIM; k0 += 64) {
        gload16(Ap0 + k0, lA + tid * 8);
        gload16(Ap1 + k0, lA + 2048 + tid * 8);
        gload16(Bp0 + k0, lB + tid * 8);
        gload16(Bp1 + k0, lB + 2048 + tid * 8);
        __syncthreads();
#pragma unroll
        for (int kk = 0; kk < 2; ++kk) {
            int xr = (((kk << 2) | quad) ^ (l15 & 7)) * 8;
            bf16x8 af = *(const bf16x8*)&lA[(wm + l15) * 64 + xr];
            bf16x8 bfv[4];
#pragma unroll
            for (int nt = 0; nt < 4; ++nt)
                bfv[nt] = *(const bf16x8*)&lB[(nt * 16 + l15) * 64 + xr];
#pragma unroll
            for (int nt = 0; nt < 4; ++nt)
                acc[nt] = __builtin_amdgcn_mfma_f32_16x16x32_bf16(af, bfv[nt], acc[nt], 0, 0, 0);
        }
        __syncthreads();
    }
    float c0 = 1.f - dt_f[0];
#pragma unroll
    for (int nt = 0; nt < 4; ++nt) {
        int col_l = nt * 16 + l15;
        float bv = bias_f[bn + col_l];
#pragma unroll
        for (int r = 0; r < 4; ++r) {
            int row_l = wm + quad * 4 + r;
            float t = fmaxf(acc[nt][r] + bv, 0.f);
            basep[(size_t)(bm + row_l) * C_DIM + bn + col_l] = c0 * t;
            lT[col_l * 64 + row_l] = f2b(t * s_row[row_l]);
        }
    }
    __syncthreads();
    // coalesced transposed store: thread -> (col_l = tid>>2, 16-row segment = tid&3)
    int col_l = tid >> 2, seg = tid & 3;
    uint4 w0 = *(const uint4*)&lT[col_l * 64 + seg * 16];
    uint4 w1 = *(const uint4*)&lT[col_l * 64 + seg * 16 + 8];
    u16* dst = TsT + (size_t)(bn + col_l) * N_NODES + bm + seg * 16;
    *(uint4*)dst = w0;
    *(uint4*)(dst + 8) = w1;
}

// ================= K3: gemm2, 64x128 tile (grid 1024 = 4 blocks/CU), BK=64 (two 32-k
// subtiles, [row][32] LDS), dim3(64,4,SPLITS), fused dvec-via-MFMA. Raw P partials
// atomically accumulated into Pacc2; d partials (B-col = s) into dvraw.
__global__ __launch_bounds__(256) void k3_gemm2(const void* __restrict__ adjraw,
        const int* __restrict__ modep,
        const u16* __restrict__ adjb, const u16* __restrict__ TsT,
        const float* __restrict__ s,
        float* __restrict__ Pacc2, float* __restrict__ dvraw) {
    __shared__ __align__(16) u16 lA[4096];   // 8 KB:  [0..2047] ksub0 (64r x 32k), [2048..] ksub1
    __shared__ __align__(16) u16 lB[8192];   // 16 KB: [0..4095] ksub0 (128r x 32k), [4096..] ksub1
    __shared__ __align__(16) u16 s_s[1024];  // 2 KB: bf16(s) for this k-chunk
    int mode = *modep;
    const u16* A = mode ? adjb : (const u16*)adjraw;
    int tid = threadIdx.x;
    int lane = tid & 63, wave = tid >> 6;
    int bm = blockIdx.x * 64, bn = blockIdx.y * 128;
    int kbase = blockIdx.z * KCHUNK;
    int wm = (wave & 1) * 32, wn = (wave >> 1) * 64;
    int quad = lane >> 4, l15 = lane & 15;
    bool do_d = (blockIdx.y == 0) && ((wave >> 1) == 0);   // wn==0 waves of bn==0 blocks

#pragma unroll
    for (int i = 0; i < 4; ++i) {
        int k = tid + i * 256;
        s_s[k] = f2b(s[kbase + k]);
    }

    const u16* Ab  = A   + (size_t)(bm + (tid >> 2)) * N_NODES + kbase + (tid & 3) * 8;
    const u16* Bb0 = TsT + (size_t)(bn + (tid >> 2)) * N_NODES + kbase + (tid & 3) * 8;
    const u16* Bb1 = TsT + (size_t)(bn + 64 + (tid >> 2)) * N_NODES + kbase + (tid & 3) * 8;

    f32x4 acc[2][4];
#pragma unroll
    for (int a = 0; a < 2; ++a)
#pragma unroll
        for (int b = 0; b < 4; ++b) acc[a][b] = (f32x4){0.f, 0.f, 0.f, 0.f};
    f32x4 accd[2];
#pragma unroll
    for (int a = 0; a < 2; ++a) accd[a] = (f32x4){0.f, 0.f, 0.f, 0.f};
    u16 dmask = (l15 == 0) ? (u16)0xFFFFu : (u16)0;

    for (int k0 = 0; k0 < KCHUNK; k0 += 64) {
        gload16(Ab + k0,       lA + tid * 8);           // A ksub0
        gload16(Ab + k0 + 32,  lA + 2048 + tid * 8);    // A ksub1
        gload16(Bb0 + k0,      lB + tid * 8);           // B rows 0-63  ksub0
        gload16(Bb1 + k0,      lB + 2048 + tid * 8);    // B rows 64-127 ksub0
        gload16(Bb0 + k0 + 32, lB + 4096 + tid * 8);    // B rows 0-63  ksub1
        gload16(Bb1 + k0 + 32, lB + 6144 + tid * 8);    // B rows 64-127 ksub1
        __syncthreads();
#pragma unroll
        for (int kk = 0; kk < 2; ++kk) {
            const u16* baseA = lA + kk * 2048;
            const u16* baseB = lB + kk * 4096;
            bf16x8 af[2], bfv[4];
#pragma unroll
            for (int mt = 0; mt < 2; ++mt) af[mt] = *(const bf16x8*)&baseA[(wm + mt * 16 + l15) * 32 + quad * 8];
#pragma unroll
            for (int nt = 0; nt < 4; ++nt) bfv[nt] = *(const bf16x8*)&baseB[(wn + nt * 16 + l15) * 32 + quad * 8];
#pragma unroll
            for (int mt = 0; mt < 2; ++mt)
#pragma unroll
                for (int nt = 0; nt < 4; ++nt)
                    acc[mt][nt] = __builtin_amdgcn_mfma_f32_16x16x32_bf16(af[mt], bfv[nt], acc[mt][nt], 0, 0, 0);
            if (do_d) {
                // B_s fragment: col 0 = s[k], cols 1..15 = 0
                u16x8 su = *(const u16x8*)&s_s[k0 + kk * 32 + quad * 8];
#pragma unroll
                for (int e = 0; e < 8; ++e) su[e] &= dmask;
                bf16x8 bs = *(bf16x8*)&su;
#pragma unroll
                for (int mt = 0; mt < 2; ++mt)
                    accd[mt] = __builtin_amdgcn_mfma_f32_16x16x32_bf16(af[mt], bs, accd[mt], 0, 0, 0);
            }
        }
        __syncthreads();
    }

#pragma unroll
    for (int mt = 0; mt < 2; ++mt) {
#pragma unroll
        for (int nt = 0; nt < 4; ++nt) {
            int col = bn + wn + nt * 16 + l15;
#pragma unroll
            for (int r = 0; r < 4; ++r) {
                int row = bm + wm + mt * 16 + quad * 4 + r;
                atomicAdd(&Pacc2[(size_t)row * C_DIM + col], acc[mt][nt][r]);
            }
        }
    }
    if (do_d && l15 == 0) {
#pragma unroll
        for (int mt = 0; mt < 2; ++mt)
#pragma unroll
            for (int r = 0; r < 4; ++r)
                atomicAdd(&dvraw[bm + wm + mt * 16 + quad * 4 + r], accd[mt][r]);
    }
}

// ================= K5: finalize both modes: out = base + (dt/EPS)*P/(d+1e-5) ============
// 256 blocks x 256 threads x 8 float4
__global__ __launch_bounds__(256) void k5_fin(const int* __restrict__ modep,
                                              const float* __restrict__ dt_f,
                                              const float* __restrict__ Pacc2,
                                              const float* __restrict__ dvraw,
                                              const float* __restrict__ Pacc_base,
                                              void* __restrict__ out) {
    int mode = *modep;
    float c1 = dt_f[0] * 4.f;                          // dt / EPS
    const float4* basep = mode ? (const float4*)out : (const float4*)Pacc_base;
#pragma unroll
    for (int i = 0; i < 8; ++i) {
        int idx = blockIdx.x * 2048 + i * 256 + threadIdx.x;   // f32x4 units, 524288 total
        float4 b = basep[idx];
        float4 p = ((const float4*)Pacc2)[idx];
        int row = idx >> 7;                            // (idx*4)/512
        float rscale = c1 / (dvraw[row] + 1e-5f);
        float4 v;
        v.x = b.x + p.x * rscale;
        v.y = b.y + p.y * rscale;
        v.z = b.z + p.z * rscale;
        v.w = b.w + p.w * rscale;
        if (mode) {
            ((float4*)out)[idx] = v;
        } else {
            ushort4 o; o.x = f2b(v.x); o.y = f2b(v.y); o.z = f2b(v.z); o.w = f2b(v.w);
            ((ushort4*)out)[idx] = o;
        }
    }
}

extern "C" void kernel_launch(void* const* d_in, const int* in_sizes, int n_in,
                              void* d_out, int out_size, void* d_ws, size_t ws_size,
                              hipStream_t stream) {
    const void* x   = d_in[0];
    const void* adj = d_in[1];
    const void* Wp  = d_in[2];
    const void* bp  = d_in[3];
    const void* Wp1 = d_in[4];
    const void* bp1 = d_in[5];
    const void* Wp2 = d_in[6];
    const void* bp2 = d_in[7];
    const void* Wf  = d_in[8];
    const void* bfc = d_in[9];
    const void* dtp = d_in[10];

    char* ws = (char*)d_ws;
    int*   modep  = (int*)(ws + OFF_MODE);
    float* dt_f   = (float*)(ws + OFF_DT);
    float* bias_f = (float*)(ws + OFF_BIAS);
    float* bp_f   = (float*)(ws + OFF_BP);
    float* bp1_f  = (float*)(ws + OFF_BP1);
    float* Wp2_f  = (float*)(ws + OFF_WP2);
    float* bp2_f  = (float*)(ws + OFF_BP2);
    float* q      = (float*)(ws + OFF_Q);
    float* s      = (float*)(ws + OFF_S);
    float* dvraw  = (float*)(ws + OFF_DV);
    u32*   WpP    = (u32*)(ws + OFF_WPP);
    u32*   Wp1P   = (u32*)(ws + OFF_WP1P);
    u16*   WfT    = (u16*)(ws + OFF_WFT);
    float* Pacc2  = (float*)(ws + OFF_PACC);
    u16*   TsT    = (u16*)(ws + OFF_TST);
    u16*   xb     = (u16*)(ws + OFF_XB);
    u16*   adjb   = (u16*)(ws + OFF_ADJB);
    float* Pacc_base = (float*)(ws + OFF_ADJB);   // bf16 mode only: adjb unused there

    hipMemsetAsync(Pacc2, 0, (size_t)N_NODES * C_DIM * sizeof(float), stream);
    hipMemsetAsync(dvraw, 0, (size_t)N_NODES * sizeof(float), stream);
    k1_prep<<<1431, 256, 0, stream>>>(adj, x, Wp, bp, Wp1, bp1, Wp2, bp2, Wf, bfc, dtp,
                                      modep, bp_f, bp1_f, Wp2_f, bp2_f, bias_f, dt_f,
                                      WpP, Wp1P, adjb, q, xb, WfT);
    k1p_pi<<<512, 256, 0, stream>>>(x, modep, xb, WpP, Wp1P, bp_f, bp1_f, Wp2_f, bp2_f, q, s);
    k2_gemm1<<<512, 256, 0, stream>>>(x, modep, s, bias_f, dt_f, xb, WfT, TsT, d_out, Pacc_base);
    k3_gemm2<<<dim3(64, 4, SPLITS), 256, 0, stream>>>(adj, modep, adjb, TsT, s, Pacc2, dvraw);
    k5_fin<<<256, 256, 0, stream>>>(modep, dt_f, Pacc2, dvraw, Pacc_base, d_out);
}

// Round 8
// 209.449 us; speedup vs baseline: 1.1466x; 1.0539x over previous
//
#include <hip/hip_runtime.h>
#include <hip/hip_bf16.h>

#define N_NODES 4096
#define C_DIM   512
#define L_DIM   64
#define SPLITS  4
#define KCHUNK  (N_NODES / SPLITS)   // 1024
#define NC      ((size_t)N_NODES * C_DIM)

typedef unsigned short u16;
typedef unsigned int   u32;
using bf16x8 = __attribute__((ext_vector_type(8))) __bf16;
using u16x8  = __attribute__((ext_vector_type(8))) unsigned short;
using f32x4  = __attribute__((ext_vector_type(4))) float;

__device__ __forceinline__ float b2f(u16 u) {
    union { unsigned int i; float f; } v; v.i = ((unsigned int)u) << 16; return v.f;
}
__device__ __forceinline__ u16 f2b(float f) {
    __bf16 h = (__bf16)f;                 // RNE
    union { __bf16 h; u16 u; } v; v.h = h; return v.u;
}
__device__ __forceinline__ void gload16(const void* g, void* l) {
    __builtin_amdgcn_global_load_lds((const __attribute__((address_space(1))) void*)g,
                                     (__attribute__((address_space(3))) void*)l,
                                     16, 0, 0);
}
// mode: 0 = bf16 inputs, 1 = f32. adj ~ U[0,1): bf16 u16 <= 0x3F80; f32 low-halves random.
__device__ __forceinline__ int detect_mode_inl(const u16* __restrict__ adj) {
    int m = 0;
#pragma unroll
    for (int i = 0; i < 64; ++i) m |= (adj[i] >= 0x8000) ? 1 : 0;
    return m;
}
__device__ __forceinline__ float ldin(const void* p, int i, int mode) {
    if (mode) return ((const float*)p)[i];
    return b2f(((const u16*)p)[i]);
}

// ---- workspace byte offsets ----
#define OFF_MODE  0
#define OFF_DT    64
#define OFF_BIAS  1024      // 512 f32
#define OFF_BP    4096      // 64 f32
#define OFF_BP1   4608      // 512 f32
#define OFF_WP2   8192      // 512 f32
#define OFF_BP2   10240     // 1 f32
#define OFF_Q     16384
#define OFF_S     32768
#define OFF_WPP   65536     // 16384 u32: packed bf16 k-pairs of Wp
#define OFF_WP1P  131072    // 16384 u32: packed bf16 k-pairs of Wp1
#define OFF_WFT   196608    // 512 KB bf16 Wf^T -> ends 720896
#define OFF_PACC  720896    // 8 MB f32: P partial slice z=0 -> ends 9109504
#define OFF_DVS   9109504   // 4 x 4096 f32 d-partial slices (64 KB) -> ends 9175040
#define OFF_TST   9437184   // 4 MB bf16 TsT[c][j] = s[j]*target[j][c]
#define OFF_XB    13631488  // 4 MB bf16 x
#define OFF_ADJB  17825792  // 32 MB bf16 adj (f32 mode); first 8MB doubles as f32 base (bf16 mode)
#define OFF_EXTRA 51380224  // 24 MB: P partial slices z=1..3 (slice mode only)
#define WS_NEEDED_SLICES 76546048ULL

// ================= K1: rowsum [0,1024) | x->bf16 [1024,1152) | Wf^T [1152,1408) |
//   packWp [1408,1416) | packWp1 [1416,1424) | smalls [1424,1431) ====
__global__ __launch_bounds__(256) void k1_prep(const void* __restrict__ adj, const void* __restrict__ x,
        const void* Wp, const void* bp, const void* Wp1, const void* bp1,
        const void* Wp2, const void* bp2, const void* Wf, const void* bfc, const void* dt,
        int* __restrict__ modep,
        float* __restrict__ bp_f, float* __restrict__ bp1_f,
        float* __restrict__ Wp2_f, float* __restrict__ bp2_f,
        float* __restrict__ bias_f, float* __restrict__ dt_f,
        u32* __restrict__ WpP, u32* __restrict__ Wp1P,
        u16* __restrict__ adjb, float* __restrict__ q, u16* __restrict__ xb,
        u16* __restrict__ WfT) {
    __shared__ float tile[32][33];
    int bid = blockIdx.x, tid = threadIdx.x;
    int mode = detect_mode_inl((const u16*)adj);
    if (bid < 1024) {
        // rowsum (+bf16 copy in f32 mode)
        int wave = tid >> 6, lane = tid & 63;
        int row = bid * 4 + wave;
        float acc = 0.f;
        if (mode) {
            const float4* rp = (const float4*)((const float*)adj + (size_t)row * N_NODES);
            ushort4* wp = (ushort4*)(adjb + (size_t)row * N_NODES);
#pragma unroll 8
            for (int it = 0; it < 16; ++it) {
                float4 v = rp[it * 64 + lane];
                acc += (v.x + v.y) + (v.z + v.w);
                ushort4 o; o.x = f2b(v.x); o.y = f2b(v.y); o.z = f2b(v.z); o.w = f2b(v.w);
                wp[it * 64 + lane] = o;
            }
        } else {
            const u16x8* rp = (const u16x8*)((const u16*)adj + (size_t)row * N_NODES);
#pragma unroll
            for (int it = 0; it < 8; ++it) {
                u16x8 v = rp[it * 64 + lane];
#pragma unroll
                for (int e = 0; e < 8; ++e) acc += b2f(v[e]);
            }
        }
#pragma unroll
        for (int off = 32; off > 0; off >>= 1) acc += __shfl_down(acc, off);
        if (lane == 0) q[row] = acc;
    } else if (bid < 1152) {
        if (mode == 0) return;
        // x -> bf16: 128 blocks x 256 threads x 16 float4 = 8 MB
        int base = (bid - 1024) * 256 + tid;
#pragma unroll
        for (int i = 0; i < 16; ++i) {
            int idx = i * 32768 + base;
            float4 v = ((const float4*)x)[idx];
            ushort4 o; o.x = f2b(v.x); o.y = f2b(v.y); o.z = f2b(v.z); o.w = f2b(v.w);
            ((ushort4*)xb)[idx] = o;
        }
    } else if (bid < 1408) {
        int g = bid - 1152;
        int tx = tid & 31, ty = tid >> 5;
        int x0 = (g & 15) * 32, y0 = (g >> 4) * 32;
        if (mode) {
            const float* src = (const float*)Wf;
#pragma unroll
            for (int r = ty; r < 32; r += 8) tile[r][tx] = src[(size_t)(y0 + r) * C_DIM + x0 + tx];
        } else {
            const u16* src = (const u16*)Wf;
#pragma unroll
            for (int r = ty; r < 32; r += 8) tile[r][tx] = b2f(src[(size_t)(y0 + r) * C_DIM + x0 + tx]);
        }
        __syncthreads();
#pragma unroll
        for (int r = ty; r < 32; r += 8)
            WfT[(size_t)(x0 + r) * C_DIM + y0 + tx] = f2b(tile[tx][r]);
    } else if (bid < 1416) {
        // WpP[k2*64 + j] = pack(Wp[2k2][j], Wp[2k2+1][j]); 8 blocks x 2048
        int base = (bid - 1408) * 2048 + tid;
#pragma unroll
        for (int i = 0; i < 8; ++i) {
            int idx = base + i * 256;                    // 0..16383
            int k2i = idx >> 6, j = idx & 63;
            float a = ldin(Wp, (2 * k2i) * L_DIM + j, mode);
            float b = ldin(Wp, (2 * k2i + 1) * L_DIM + j, mode);
            WpP[idx] = (u32)f2b(a) | ((u32)f2b(b) << 16);
        }
    } else if (bid < 1424) {
        // Wp1P[jj2*512 + m] = pack(Wp1[2jj2][m], Wp1[2jj2+1][m]); 8 blocks x 2048
        int base = (bid - 1416) * 2048 + tid;
#pragma unroll
        for (int i = 0; i < 8; ++i) {
            int idx = base + i * 256;                    // 0..16383
            int jj2 = idx >> 9, m = idx & 511;
            float a = ldin(Wp1, (2 * jj2) * C_DIM + m, mode);
            float b = ldin(Wp1, (2 * jj2 + 1) * C_DIM + m, mode);
            Wp1P[idx] = (u32)f2b(a) | ((u32)f2b(b) << 16);
        }
    } else {
        if (bid == 1424 && tid == 0) *modep = mode;
        int idx = (bid - 1424) * 256 + tid;
        if (idx < 64)           bp_f[idx]          = ldin(bp,  idx, mode);
        else if (idx < 576)     bp1_f[idx - 64]    = ldin(bp1, idx - 64, mode);
        else if (idx < 1088)    Wp2_f[idx - 576]   = ldin(Wp2, idx - 576, mode);
        else if (idx == 1088)   bp2_f[0]           = ldin(bp2, 0, mode);
        else if (idx < 1601)    bias_f[idx - 1089] = ldin(bfc, idx - 1089, mode);
        else if (idx == 1601)   dt_f[0]            = ldin(dt, 0, mode);
    }
}

// ================= K1p: pi-MLP (512 blocks x 8 rows), packed bf16 weights; writes s = pi/q ====
__global__ __launch_bounds__(256) void k1p_pi(const void* __restrict__ xraw,
        const int* __restrict__ modep, const u16* __restrict__ xb,
        const u32* __restrict__ WpP, const u32* __restrict__ Wp1P,
        const float* __restrict__ bp_f,  const float* __restrict__ bp1_f,
        const float* __restrict__ Wp2_f, const float* __restrict__ bp2_f,
        const float* __restrict__ q, float* __restrict__ s) {
    __shared__ __align__(16) char smem[26880];
    int bid = blockIdx.x, tid = threadIdx.x;
    int mode = *modep;
    float (*sx)[C_DIM]      = (float(*)[C_DIM])smem;                 // 16 KB
    float (*red)[8][L_DIM]  = (float(*)[8][L_DIM])(smem + 16384);    // 8 KB
    float (*sz)[L_DIM]      = (float(*)[L_DIM])(smem + 24576);       // 2 KB
    float (*rw)[8]          = (float(*)[8])(smem + 26624);           // 128 B
    int i0 = bid * 8;
    const u16* xsrc = mode ? xb : (const u16*)xraw;
    const u16x8* xp = (const u16x8*)(xsrc + (size_t)i0 * C_DIM);
#pragma unroll
    for (int r = 0; r < 2; ++r) {
        u16x8 v = xp[tid + 256 * r];
        float* dstf = &sx[0][0] + (size_t)(tid + 256 * r) * 8;
#pragma unroll
        for (int e = 0; e < 8; ++e) dstf[e] = b2f(v[e]);
    }
    __syncthreads();
    // z-phase: thread (part = tid>>6, j = tid&63) covers k in [part*128, +128)
    int j = tid & 63, part = tid >> 6;
    float za[8];
#pragma unroll
    for (int n = 0; n < 8; ++n) za[n] = 0.f;
    const u32* wp = WpP + part * 4096 + j;
#pragma unroll 8
    for (int kk = 0; kk < 64; ++kk) {
        u32 w = wp[kk * 64];
        float wa = b2f((u16)(w & 0xFFFF)), wb = b2f((u16)(w >> 16));
        int k = part * 128 + kk * 2;
#pragma unroll
        for (int n = 0; n < 8; ++n) za[n] += sx[n][k] * wa + sx[n][k + 1] * wb;
    }
#pragma unroll
    for (int n = 0; n < 8; ++n) red[part][n][j] = za[n];
    __syncthreads();
#pragma unroll
    for (int r = 0; r < 2; ++r) {
        int idx = tid + r * 256; int n = idx >> 6, jj = idx & 63;
        sz[n][jj] = red[0][n][jj] + red[1][n][jj] + red[2][n][jj] + red[3][n][jj] + bp_f[jj];
    }
    __syncthreads();
    // h-phase: thread owns m0 = tid, m1 = tid+256
    int m0 = tid, m1 = tid + 256;
    float h0[8], h1[8];
    float b0 = bp1_f[m0], b1 = bp1_f[m1];
#pragma unroll
    for (int n = 0; n < 8; ++n) { h0[n] = b0; h1[n] = b1; }
    const u32* w1p = Wp1P + m0;
#pragma unroll 4
    for (int jj2 = 0; jj2 < 32; ++jj2) {
        u32 w0 = w1p[jj2 * 512], w1 = w1p[jj2 * 512 + 256];
        float w0a = b2f((u16)(w0 & 0xFFFF)), w0b = b2f((u16)(w0 >> 16));
        float w1a = b2f((u16)(w1 & 0xFFFF)), w1b = b2f((u16)(w1 >> 16));
#pragma unroll
        for (int n = 0; n < 8; ++n) {
            float za_ = sz[n][2 * jj2], zb_ = sz[n][2 * jj2 + 1];
            h0[n] += za_ * w0a + zb_ * w0b;
            h1[n] += za_ * w1a + zb_ * w1b;
        }
    }
    float w2a = Wp2_f[m0], w2b = Wp2_f[m1];
    float p[8];
#pragma unroll
    for (int n = 0; n < 8; ++n)
        p[n] = fmaxf(h0[n], 0.f) * w2a + fmaxf(h1[n], 0.f) * w2b;
#pragma unroll
    for (int off = 32; off > 0; off >>= 1)
#pragma unroll
        for (int n = 0; n < 8; ++n) p[n] += __shfl_down(p[n], off);
    int lane = tid & 63, wave = tid >> 6;
    if (lane == 0) {
#pragma unroll
        for (int n = 0; n < 8; ++n) rw[wave][n] = p[n];
    }
    __syncthreads();
    if (tid < 8) {
        float tot = rw[0][tid] + rw[1][tid] + rw[2][tid] + rw[3][tid] + bp2_f[0];
        float pi = 1.f / (1.f + expf(-tot));
        s[i0 + tid] = pi / q[i0 + tid];
    }
}

// ================= K2: gemm1 BK=64 swizzled + fused s-scale/transpose (512 blocks) ====
// base = (1-dt)*t -> out (f32 mode) / Pacc_base (bf16 mode); TsT[col][row] = bf16(t*s[row])
__global__ __launch_bounds__(256) void k2_gemm1(const void* __restrict__ xraw,
        const int* __restrict__ modep,
        const float* __restrict__ s, const float* __restrict__ bias_f, const float* __restrict__ dt_f,
        const u16* __restrict__ xb, const u16* __restrict__ WfT,
        u16* __restrict__ TsT, void* __restrict__ out, float* __restrict__ Pacc_base) {
    __shared__ __align__(16) char smem[16640];
    int bid = blockIdx.x, tid = threadIdx.x;
    int mode = *modep;
    u16* lA = (u16*)smem;                    // 8 KB: 64 rows x 64 elem
    u16* lB = (u16*)(smem + 8192);           // 8 KB
    u16* lT = (u16*)smem;                    // 8 KB, aliases lA after main loop
    float* s_row = (float*)(smem + 16384);   // 256 B
    int lane = tid & 63, wave = tid >> 6;
    int bm = (bid & 63) * 64, bn = (bid >> 6) * 64;
    if (tid < 64) s_row[tid] = s[bm + tid];
    const u16* Axb = mode ? xb : (const u16*)xraw;
    float* basep = mode ? (float*)out : Pacc_base;
    int quad = lane >> 4, l15 = lane & 15;
    int wm = wave * 16;
    int trow = tid >> 3;                       // 0..31
    int xslot = (tid & 7) ^ (trow & 7);        // inverse-swizzled global slot
    const u16* Ap0 = Axb + (size_t)(bm + trow) * C_DIM + xslot * 8;
    const u16* Ap1 = Axb + (size_t)(bm + 32 + trow) * C_DIM + xslot * 8;
    const u16* Bp0 = WfT + (size_t)(bn + trow) * C_DIM + xslot * 8;
    const u16* Bp1 = WfT + (size_t)(bn + 32 + trow) * C_DIM + xslot * 8;
    f32x4 acc[4];
#pragma unroll
    for (int nt = 0; nt < 4; ++nt) acc[nt] = (f32x4){0.f, 0.f, 0.f, 0.f};
    for (int k0 = 0; k0 < C_DIM; k0 += 64) {
        gload16(Ap0 + k0, lA + tid * 8);
        gload16(Ap1 + k0, lA + 2048 + tid * 8);
        gload16(Bp0 + k0, lB + tid * 8);
        gload16(Bp1 + k0, lB + 2048 + tid * 8);
        __syncthreads();
#pragma unroll
        for (int kk = 0; kk < 2; ++kk) {
            int xr = (((kk << 2) | quad) ^ (l15 & 7)) * 8;
            bf16x8 af = *(const bf16x8*)&lA[(wm + l15) * 64 + xr];
            bf16x8 bfv[4];
#pragma unroll
            for (int nt = 0; nt < 4; ++nt)
                bfv[nt] = *(const bf16x8*)&lB[(nt * 16 + l15) * 64 + xr];
#pragma unroll
            for (int nt = 0; nt < 4; ++nt)
                acc[nt] = __builtin_amdgcn_mfma_f32_16x16x32_bf16(af, bfv[nt], acc[nt], 0, 0, 0);
        }
        __syncthreads();
    }
    float c0 = 1.f - dt_f[0];
#pragma unroll
    for (int nt = 0; nt < 4; ++nt) {
        int col_l = nt * 16 + l15;
        float bv = bias_f[bn + col_l];
#pragma unroll
        for (int r = 0; r < 4; ++r) {
            int row_l = wm + quad * 4 + r;
            float t = fmaxf(acc[nt][r] + bv, 0.f);
            basep[(size_t)(bm + row_l) * C_DIM + bn + col_l] = c0 * t;
            lT[col_l * 64 + row_l] = f2b(t * s_row[row_l]);
        }
    }
    __syncthreads();
    // coalesced transposed store: thread -> (col_l = tid>>2, 16-row segment = tid&3)
    int col_l = tid >> 2, seg = tid & 3;
    uint4 w0 = *(const uint4*)&lT[col_l * 64 + seg * 16];
    uint4 w1 = *(const uint4*)&lT[col_l * 64 + seg * 16 + 8];
    u16* dst = TsT + (size_t)(bn + col_l) * N_NODES + bm + seg * 16;
    *(uint4*)dst = w0;
    *(uint4*)(dst + 8) = w1;
}

// ================= K3: gemm2 128x128 tile, BK=64 (two 32-k subtiles, [row][32] LDS),
// dim3(32,4,SPLITS), fused dvec-via-MFMA. Slice mode: plain stores into per-z P slice
// and per-z d slice (no atomics). Atomic fallback if workspace too small.
__global__ __launch_bounds__(256) void k3_gemm2(const void* __restrict__ adjraw,
        const int* __restrict__ modep,
        const u16* __restrict__ adjb, const u16* __restrict__ TsT,
        const float* __restrict__ s,
        float* __restrict__ p0, float* __restrict__ pex,
        float* __restrict__ dvs, int use_slices) {
    __shared__ __align__(16) u16 lA[8192];   // 16 KB: [0..4095] k-sub 0, [4096..8191] k-sub 1
    __shared__ __align__(16) u16 lB[8192];   // 16 KB
    __shared__ __align__(16) u16 s_s[1024];  // 2 KB: bf16(s) for this k-chunk
    int mode = *modep;
    const u16* A = mode ? adjb : (const u16*)adjraw;
    int tid = threadIdx.x;
    int lane = tid & 63, wave = tid >> 6;
    int bm = blockIdx.x * 128, bn = blockIdx.y * 128;
    int z = blockIdx.z;
    int kbase = z * KCHUNK;
    int wm = (wave & 1) * 64, wn = (wave >> 1) * 64;
    int quad = lane >> 4, l15 = lane & 15;
    bool do_d = (blockIdx.y == 0) && (wave < 2);   // wn==0 waves of bn==0 blocks

#pragma unroll
    for (int i = 0; i < 4; ++i) {
        int k = tid + i * 256;
        s_s[k] = f2b(s[kbase + k]);
    }

    const u16* Ab0 = A + (size_t)(bm + (tid >> 2)) * N_NODES + kbase + (tid & 3) * 8;
    const u16* Ab1 = A + (size_t)(bm + 64 + (tid >> 2)) * N_NODES + kbase + (tid & 3) * 8;
    const u16* Bb0 = TsT + (size_t)(bn + (tid >> 2)) * N_NODES + kbase + (tid & 3) * 8;
    const u16* Bb1 = TsT + (size_t)(bn + 64 + (tid >> 2)) * N_NODES + kbase + (tid & 3) * 8;
    u16* la00 = lA + tid * 8;        u16* la01 = lA + 2048 + tid * 8;   // k-sub 0
    u16* la10 = lA + 4096 + tid * 8; u16* la11 = lA + 6144 + tid * 8;   // k-sub 1
    u16* lb00 = lB + tid * 8;        u16* lb01 = lB + 2048 + tid * 8;
    u16* lb10 = lB + 4096 + tid * 8; u16* lb11 = lB + 6144 + tid * 8;

    f32x4 acc[4][4];
#pragma unroll
    for (int a = 0; a < 4; ++a)
#pragma unroll
        for (int b = 0; b < 4; ++b) acc[a][b] = (f32x4){0.f, 0.f, 0.f, 0.f};
    f32x4 accd[4];
#pragma unroll
    for (int a = 0; a < 4; ++a) accd[a] = (f32x4){0.f, 0.f, 0.f, 0.f};
    u16 dmask = (l15 == 0) ? (u16)0xFFFFu : (u16)0;

    for (int k0 = 0; k0 < KCHUNK; k0 += 64) {
        gload16(Ab0 + k0, la00);
        gload16(Ab1 + k0, la01);
        gload16(Ab0 + k0 + 32, la10);
        gload16(Ab1 + k0 + 32, la11);
        gload16(Bb0 + k0, lb00);
        gload16(Bb1 + k0, lb01);
        gload16(Bb0 + k0 + 32, lb10);
        gload16(Bb1 + k0 + 32, lb11);
        __syncthreads();
#pragma unroll
        for (int kk = 0; kk < 2; ++kk) {
            const u16* baseA = lA + kk * 4096;
            const u16* baseB = lB + kk * 4096;
            bf16x8 af[4], bfv[4];
#pragma unroll
            for (int mt = 0; mt < 4; ++mt) af[mt] = *(const bf16x8*)&baseA[(wm + mt * 16 + l15) * 32 + quad * 8];
#pragma unroll
            for (int nt = 0; nt < 4; ++nt) bfv[nt] = *(const bf16x8*)&baseB[(wn + nt * 16 + l15) * 32 + quad * 8];
#pragma unroll
            for (int mt = 0; mt < 4; ++mt)
#pragma unroll
                for (int nt = 0; nt < 4; ++nt)
                    acc[mt][nt] = __builtin_amdgcn_mfma_f32_16x16x32_bf16(af[mt], bfv[nt], acc[mt][nt], 0, 0, 0);
            if (do_d) {
                // B_s fragment: col 0 = s[k], cols 1..15 = 0
                u16x8 su = *(const u16x8*)&s_s[k0 + kk * 32 + quad * 8];
#pragma unroll
                for (int e = 0; e < 8; ++e) su[e] &= dmask;
                bf16x8 bs = *(bf16x8*)&su;
#pragma unroll
                for (int mt = 0; mt < 4; ++mt)
                    accd[mt] = __builtin_amdgcn_mfma_f32_16x16x32_bf16(af[mt], bs, accd[mt], 0, 0, 0);
            }
        }
        __syncthreads();
    }

    if (use_slices) {
        float* dst = (z == 0) ? p0 : (pex + (size_t)(z - 1) * NC);
#pragma unroll
        for (int mt = 0; mt < 4; ++mt) {
#pragma unroll
            for (int nt = 0; nt < 4; ++nt) {
                int col = bn + wn + nt * 16 + l15;
#pragma unroll
                for (int r = 0; r < 4; ++r) {
                    int row = bm + wm + mt * 16 + quad * 4 + r;
                    dst[(size_t)row * C_DIM + col] = acc[mt][nt][r];
                }
            }
        }
        if (do_d && l15 == 0) {
#pragma unroll
            for (int mt = 0; mt < 4; ++mt)
#pragma unroll
                for (int r = 0; r < 4; ++r)
                    dvs[z * N_NODES + bm + wm + mt * 16 + quad * 4 + r] = accd[mt][r];
        }
    } else {
#pragma unroll
        for (int mt = 0; mt < 4; ++mt) {
#pragma unroll
            for (int nt = 0; nt < 4; ++nt) {
                int col = bn + wn + nt * 16 + l15;
#pragma unroll
                for (int r = 0; r < 4; ++r) {
                    int row = bm + wm + mt * 16 + quad * 4 + r;
                    atomicAdd(&p0[(size_t)row * C_DIM + col], acc[mt][nt][r]);
                }
            }
        }
        if (do_d && l15 == 0) {
#pragma unroll
            for (int mt = 0; mt < 4; ++mt)
#pragma unroll
                for (int r = 0; r < 4; ++r)
                    atomicAdd(&dvs[bm + wm + mt * 16 + quad * 4 + r], accd[mt][r]);
        }
    }
}

// ================= K5: reduce slices + finalize: out = base + (dt/EPS)*P/(d+1e-5) ======
// 256 blocks x 256 threads x 8 float4
__global__ __launch_bounds__(256) void k5_fin(const int* __restrict__ modep,
                                              const float* __restrict__ dt_f,
                                              const float* __restrict__ p0,
                                              const float* __restrict__ pex,
                                              const float* __restrict__ dvs,
                                              const float* __restrict__ Pacc_base,
                                              void* __restrict__ out, int nsl) {
    int mode = *modep;
    float c1 = dt_f[0] * 4.f;                          // dt / EPS
    const float4* basep = mode ? (const float4*)out : (const float4*)Pacc_base;
#pragma unroll
    for (int i = 0; i < 8; ++i) {
        int idx = blockIdx.x * 2048 + i * 256 + threadIdx.x;   // f32x4 units, 524288 total
        float4 b = basep[idx];
        float4 p = ((const float4*)p0)[idx];
        int row = idx >> 7;                            // (idx*4)/512
        float d = dvs[row];
        if (nsl == 4) {
            float4 p1 = ((const float4*)pex)[idx];
            float4 p2 = ((const float4*)(pex + NC))[idx];
            float4 p3 = ((const float4*)(pex + 2 * NC))[idx];
            p.x += p1.x + p2.x + p3.x;
            p.y += p1.y + p2.y + p3.y;
            p.z += p1.z + p2.z + p3.z;
            p.w += p1.w + p2.w + p3.w;
            d += dvs[N_NODES + row] + dvs[2 * N_NODES + row] + dvs[3 * N_NODES + row];
        }
        float rscale = c1 / (d + 1e-5f);
        float4 v;
        v.x = b.x + p.x * rscale;
        v.y = b.y + p.y * rscale;
        v.z = b.z + p.z * rscale;
        v.w = b.w + p.w * rscale;
        if (mode) {
            ((float4*)out)[idx] = v;
        } else {
            ushort4 o; o.x = f2b(v.x); o.y = f2b(v.y); o.z = f2b(v.z); o.w = f2b(v.w);
            ((ushort4*)out)[idx] = o;
        }
    }
}

extern "C" void kernel_launch(void* const* d_in, const int* in_sizes, int n_in,
                              void* d_out, int out_size, void* d_ws, size_t ws_size,
                              hipStream_t stream) {
    const void* x   = d_in[0];
    const void* adj = d_in[1];
    const void* Wp  = d_in[2];
    const void* bp  = d_in[3];
    const void* Wp1 = d_in[4];
    const void* bp1 = d_in[5];
    const void* Wp2 = d_in[6];
    const void* bp2 = d_in[7];
    const void* Wf  = d_in[8];
    const void* bfc = d_in[9];
    const void* dtp = d_in[10];

    char* ws = (char*)d_ws;
    int*   modep  = (int*)(ws + OFF_MODE);
    float* dt_f   = (float*)(ws + OFF_DT);
    float* bias_f = (float*)(ws + OFF_BIAS);
    float* bp_f   = (float*)(ws + OFF_BP);
    float* bp1_f  = (float*)(ws + OFF_BP1);
    float* Wp2_f  = (float*)(ws + OFF_WP2);
    float* bp2_f  = (float*)(ws + OFF_BP2);
    float* q      = (float*)(ws + OFF_Q);
    float* s      = (float*)(ws + OFF_S);
    u32*   WpP    = (u32*)(ws + OFF_WPP);
    u32*   Wp1P   = (u32*)(ws + OFF_WP1P);
    u16*   WfT    = (u16*)(ws + OFF_WFT);
    float* p0     = (float*)(ws + OFF_PACC);
    float* dvs    = (float*)(ws + OFF_DVS);
    u16*   TsT    = (u16*)(ws + OFF_TST);
    u16*   xb     = (u16*)(ws + OFF_XB);
    u16*   adjb   = (u16*)(ws + OFF_ADJB);
    float* pex    = (float*)(ws + OFF_EXTRA);
    float* Pacc_base = (float*)(ws + OFF_ADJB);   // bf16 mode only: adjb unused there

    int use_slices = (ws_size >= (size_t)WS_NEEDED_SLICES) ? 1 : 0;
    if (!use_slices) {
        hipMemsetAsync(p0, 0, NC * sizeof(float), stream);
        hipMemsetAsync(dvs, 0, (size_t)N_NODES * sizeof(float), stream);
    }
    k1_prep<<<1431, 256, 0, stream>>>(adj, x, Wp, bp, Wp1, bp1, Wp2, bp2, Wf, bfc, dtp,
                                      modep, bp_f, bp1_f, Wp2_f, bp2_f, bias_f, dt_f,
                                      WpP, Wp1P, adjb, q, xb, WfT);
    k1p_pi<<<512, 256, 0, stream>>>(x, modep, xb, WpP, Wp1P, bp_f, bp1_f, Wp2_f, bp2_f, q, s);
    k2_gemm1<<<512, 256, 0, stream>>>(x, modep, s, bias_f, dt_f, xb, WfT, TsT, d_out, Pacc_base);
    k3_gemm2<<<dim3(32, 4, SPLITS), 256, 0, stream>>>(adj, modep, adjb, TsT, s,
                                                      p0, pex, dvs, use_slices);
    k5_fin<<<256, 256, 0, stream>>>(modep, dt_f, p0, pex, dvs, Pacc_base, d_out,
                                    use_slices ? 4 : 1);
}